// Round 1
// baseline (1224.908 us; speedup 1.0000x reference)
//
#include <hip/hip_runtime.h>
#include <hip/hip_bf16.h>

// Problem constants (match reference exactly)
constexpr int S_LEN   = 4096;
constexpr int EMB     = 768;
constexpr int NH      = 12;
constexpr int DK      = 64;        // EMB / NH
constexpr int QKV_DIM = 3 * EMB;   // 2304

// ---------------------------------------------------------------------------
// NT-GEMM: C[M,N] = A[M,K] @ B[N,K]^T (+ optional bias[N])
// 128x128 block tile, BK=16, 256 threads, 8x8 per-thread register tile.
// LDS is k-major ([BK][BM+4]) so the inner-loop fragment reads are contiguous
// (compiler emits ds_read_b128 pairs).
// ---------------------------------------------------------------------------
constexpr int BM = 128, BN = 128, BK = 16;

__global__ __launch_bounds__(256) void gemm_nt_f32(
    const float* __restrict__ A, const float* __restrict__ Bm,
    const float* __restrict__ bias, float* __restrict__ C,
    int M, int N, int K)
{
  __shared__ __align__(16) float As[BK][BM + 4];
  __shared__ __align__(16) float Bs[BK][BN + 4];

  const int tid  = threadIdx.x;
  const int brow = blockIdx.x * BM;
  const int bcol = blockIdx.y * BN;
  const int tr   = (tid >> 4) << 3;   // 0..120 step 8 (row in tile)
  const int tc   = (tid & 15) << 3;   // 0..120 step 8 (col in tile)

  float acc[8][8] = {};

  for (int k0 = 0; k0 < K; k0 += BK) {
    // Stage A and B tiles: 128x16 = 2048 floats each, 8 scalars per thread.
    // Global: 16 consecutive lanes read 16 consecutive k's (64B) -> coalesced.
    // LDS write As[kk][r]: bank (4*kk + r) % 32 -> mild conflicts, cheap.
#pragma unroll
    for (int i = 0; i < 8; ++i) {
      int idx = tid + (i << 8);        // 0..2047
      int kk  = idx & (BK - 1);
      int r   = idx >> 4;
      As[kk][r] = A [(size_t)(brow + r) * K + k0 + kk];
      Bs[kk][r] = Bm[(size_t)(bcol + r) * K + k0 + kk];
    }
    __syncthreads();

#pragma unroll
    for (int kk = 0; kk < BK; ++kk) {
      float a[8], b[8];
#pragma unroll
      for (int i = 0; i < 8; ++i) a[i] = As[kk][tr + i];
#pragma unroll
      for (int j = 0; j < 8; ++j) b[j] = Bs[kk][tc + j];
#pragma unroll
      for (int i = 0; i < 8; ++i)
#pragma unroll
        for (int j = 0; j < 8; ++j)
          acc[i][j] += a[i] * b[j];
    }
    __syncthreads();
  }

#pragma unroll
  for (int i = 0; i < 8; ++i) {
    size_t row = (size_t)(brow + tr + i) * N + bcol + tc;
#pragma unroll
    for (int j = 0; j < 8; j += 4) {
      float4 v;
      v.x = acc[i][j + 0];
      v.y = acc[i][j + 1];
      v.z = acc[i][j + 2];
      v.w = acc[i][j + 3];
      if (bias != nullptr) {
        v.x += bias[bcol + tc + j + 0];
        v.y += bias[bcol + tc + j + 1];
        v.z += bias[bcol + tc + j + 2];
        v.w += bias[bcol + tc + j + 3];
      }
      *reinterpret_cast<float4*>(&C[row + j]) = v;
    }
  }
}

// ---------------------------------------------------------------------------
// Flash attention, fp32. One block = (64-query tile, one head). 256 threads.
// qkv layout: qkv[s][f], f = (c*NH + h)*DK + d, c in {q,k,v}.
//   Q[h][s][d] = qkv[s*2304 +        h*64 + d]
//   K[h][s][d] = qkv[s*2304 +  768 + h*64 + d]
//   V[h][s][d] = qkv[s*2304 + 1536 + h*64 + d]
// Per 64-key tile: scores (GEMM-style 4x4/thread) -> online softmax (4
// threads per row, shfl combine) -> PV accumulate (4x4/thread).
// ---------------------------------------------------------------------------
__global__ __launch_bounds__(256) void flash_attn_f32(
    const float* __restrict__ qkv, float* __restrict__ attn_out)
{
  constexpr int TQ = 64, TK = 64, PAD = 68;
  __shared__ __align__(16) float Qs[DK][PAD];   // d-major: Qs[d][q]
  __shared__ __align__(16) float Ks[DK][PAD];   // d-major: Ks[d][t]
  __shared__ __align__(16) float Vs[TK][PAD];   // t-major: Vs[t][d]
  __shared__ __align__(16) float Ps[TQ][PAD];   // scores / P: Ps[q][t]
  __shared__ float scale_s[TQ];
  __shared__ float l_s[TQ];

  const int tid = threadIdx.x;
  const int q0  = blockIdx.x * TQ;
  const int h   = blockIdx.y;

  // GEMM-role mapping (scores + PV): 16x16 threads, 4x4 tile each
  const int ty = tid >> 4, tx = tid & 15;
  const int r0 = ty << 2;          // query row base (0..60)
  const int c0 = tx << 2;          // key col / d col base (0..60)

  // softmax-role mapping: 4 threads per query row
  const int srow = tid >> 2;       // 0..63
  const int sq   = tid & 3;        // quarter of the 64 keys

  const float* Qg = qkv + (size_t)q0 * QKV_DIM + h * DK;
  const float* Kg = qkv + EMB + h * DK;
  const float* Vg = qkv + 2 * EMB + h * DK;

  // Stage Q tile (transpose to d-major). 64x64 floats, float4 global loads.
#pragma unroll
  for (int i = 0; i < 4; ++i) {
    int idx = tid + (i << 8);              // 0..1023
    int q   = idx >> 4;
    int d4  = (idx & 15) << 2;
    float4 qv = *reinterpret_cast<const float4*>(&Qg[(size_t)q * QKV_DIM + d4]);
    Qs[d4 + 0][q] = qv.x; Qs[d4 + 1][q] = qv.y;
    Qs[d4 + 2][q] = qv.z; Qs[d4 + 3][q] = qv.w;
  }

  float m_reg = -1e30f, l_reg = 0.0f;
  float acc[4][4] = {};

  for (int t0 = 0; t0 < S_LEN; t0 += TK) {
    // ---- stage K (transposed) and V (natural) ----
#pragma unroll
    for (int i = 0; i < 4; ++i) {
      int idx = tid + (i << 8);
      int t   = idx >> 4;
      int d4  = (idx & 15) << 2;
      float4 kv = *reinterpret_cast<const float4*>(&Kg[(size_t)(t0 + t) * QKV_DIM + d4]);
      Ks[d4 + 0][t] = kv.x; Ks[d4 + 1][t] = kv.y;
      Ks[d4 + 2][t] = kv.z; Ks[d4 + 3][t] = kv.w;
      float4 vv = *reinterpret_cast<const float4*>(&Vg[(size_t)(t0 + t) * QKV_DIM + d4]);
      *reinterpret_cast<float4*>(&Vs[t][d4]) = vv;
    }
    __syncthreads();

    // ---- scores: S[q][t] = (1/8) * sum_d Q[q][d] K[t][d] ----
    float sc[4][4] = {};
#pragma unroll 16
    for (int d = 0; d < DK; ++d) {
      float a0 = Qs[d][r0 + 0], a1 = Qs[d][r0 + 1];
      float a2 = Qs[d][r0 + 2], a3 = Qs[d][r0 + 3];
      float b0 = Ks[d][c0 + 0], b1 = Ks[d][c0 + 1];
      float b2 = Ks[d][c0 + 2], b3 = Ks[d][c0 + 3];
      sc[0][0] += a0 * b0; sc[0][1] += a0 * b1; sc[0][2] += a0 * b2; sc[0][3] += a0 * b3;
      sc[1][0] += a1 * b0; sc[1][1] += a1 * b1; sc[1][2] += a1 * b2; sc[1][3] += a1 * b3;
      sc[2][0] += a2 * b0; sc[2][1] += a2 * b1; sc[2][2] += a2 * b2; sc[2][3] += a2 * b3;
      sc[3][0] += a3 * b0; sc[3][1] += a3 * b1; sc[3][2] += a3 * b2; sc[3][3] += a3 * b3;
    }
#pragma unroll
    for (int i = 0; i < 4; ++i) {
      float4 v;
      v.x = sc[i][0] * 0.125f; v.y = sc[i][1] * 0.125f;
      v.z = sc[i][2] * 0.125f; v.w = sc[i][3] * 0.125f;
      *reinterpret_cast<float4*>(&Ps[r0 + i][c0]) = v;
    }
    __syncthreads();

    // ---- online softmax: 4 threads per row, 16 scores each ----
    {
      float p[16];
#pragma unroll
      for (int k = 0; k < 4; ++k) {
        float4 v = *reinterpret_cast<const float4*>(&Ps[srow][(sq << 4) + (k << 2)]);
        p[4 * k + 0] = v.x; p[4 * k + 1] = v.y;
        p[4 * k + 2] = v.z; p[4 * k + 3] = v.w;
      }
      float tmax = p[0];
#pragma unroll
      for (int k = 1; k < 16; ++k) tmax = fmaxf(tmax, p[k]);
      tmax = fmaxf(tmax, __shfl_xor(tmax, 1));
      tmax = fmaxf(tmax, __shfl_xor(tmax, 2));
      float mnew = fmaxf(m_reg, tmax);
      float scl  = __expf(m_reg - mnew);
      float sum  = 0.0f;
#pragma unroll
      for (int k = 0; k < 16; ++k) {
        p[k] = __expf(p[k] - mnew);
        sum += p[k];
      }
      sum += __shfl_xor(sum, 1);
      sum += __shfl_xor(sum, 2);
      l_reg = l_reg * scl + sum;
      m_reg = mnew;
      if (sq == 0) scale_s[srow] = scl;
#pragma unroll
      for (int k = 0; k < 4; ++k) {
        float4 v;
        v.x = p[4 * k + 0]; v.y = p[4 * k + 1];
        v.z = p[4 * k + 2]; v.w = p[4 * k + 3];
        *reinterpret_cast<float4*>(&Ps[srow][(sq << 4) + (k << 2)]) = v;
      }
    }
    __syncthreads();

    // ---- PV: acc = acc*scale + P @ V ----
#pragma unroll
    for (int i = 0; i < 4; ++i) {
      float scl = scale_s[r0 + i];
      acc[i][0] *= scl; acc[i][1] *= scl; acc[i][2] *= scl; acc[i][3] *= scl;
    }
#pragma unroll 4
    for (int t = 0; t < TK; t += 4) {
      float pa[4][4], vb[4][4];
#pragma unroll
      for (int i = 0; i < 4; ++i) {
        float4 pv = *reinterpret_cast<const float4*>(&Ps[r0 + i][t]);
        pa[i][0] = pv.x; pa[i][1] = pv.y; pa[i][2] = pv.z; pa[i][3] = pv.w;
      }
#pragma unroll
      for (int k = 0; k < 4; ++k) {
        float4 vv = *reinterpret_cast<const float4*>(&Vs[t + k][c0]);
        vb[k][0] = vv.x; vb[k][1] = vv.y; vb[k][2] = vv.z; vb[k][3] = vv.w;
      }
#pragma unroll
      for (int k = 0; k < 4; ++k)
#pragma unroll
        for (int i = 0; i < 4; ++i) {
          acc[i][0] += pa[i][k] * vb[k][0];
          acc[i][1] += pa[i][k] * vb[k][1];
          acc[i][2] += pa[i][k] * vb[k][2];
          acc[i][3] += pa[i][k] * vb[k][3];
        }
    }
    __syncthreads();
  }

  // publish row sums, then normalize + write out in [S, EMB] layout
  if (sq == 0) l_s[srow] = l_reg;
  __syncthreads();

#pragma unroll
  for (int i = 0; i < 4; ++i) {
    float inv = 1.0f / l_s[r0 + i];
    float4 v;
    v.x = acc[i][0] * inv; v.y = acc[i][1] * inv;
    v.z = acc[i][2] * inv; v.w = acc[i][3] * inv;
    *reinterpret_cast<float4*>(
        &attn_out[(size_t)(q0 + r0 + i) * EMB + h * DK + c0]) = v;
  }
}

// ---------------------------------------------------------------------------
// Launch: qkv GEMM -> flash attention -> output GEMM (+bias)
// Workspace: qkv [4096][2304] f32 (37.75 MB) + attn_out [4096][768] f32
// (12.6 MB) = 48 MB of d_ws.
// ---------------------------------------------------------------------------
extern "C" void kernel_launch(void* const* d_in, const int* in_sizes, int n_in,
                              void* d_out, int out_size, void* d_ws, size_t ws_size,
                              hipStream_t stream) {
  const float* x     = (const float*)d_in[0];
  const float* w_qkv = (const float*)d_in[1];
  const float* w_out = (const float*)d_in[2];
  const float* b_out = (const float*)d_in[3];
  float* out = (float*)d_out;

  float* qkv      = (float*)d_ws;                         // [S_LEN][QKV_DIM]
  float* attn_out = qkv + (size_t)S_LEN * QKV_DIM;        // [S_LEN][EMB]

  dim3 blk(256);

  // qkv = x @ w_qkv^T : [4096,768] x [2304,768]^T -> [4096,2304]
  gemm_nt_f32<<<dim3(S_LEN / BM, QKV_DIM / BN), blk, 0, stream>>>(
      x, w_qkv, nullptr, qkv, S_LEN, QKV_DIM, EMB);

  // attention per head -> attn_out [4096,768]
  flash_attn_f32<<<dim3(S_LEN / 64, NH), blk, 0, stream>>>(qkv, attn_out);

  // out = attn_out @ w_out^T + b_out : [4096,768] x [768,768]^T -> [4096,768]
  gemm_nt_f32<<<dim3(S_LEN / BM, EMB / BN), blk, 0, stream>>>(
      attn_out, w_out, b_out, out, S_LEN, EMB, EMB);
}

// Round 2
// 719.145 us; speedup vs baseline: 1.7033x; 1.7033x over previous
//
#include <hip/hip_runtime.h>
#include <hip/hip_bf16.h>

constexpr int S_LEN   = 4096;
constexpr int EMB     = 768;
constexpr int NH      = 12;
constexpr int DK      = 64;
constexpr int QKV_DIM = 3 * EMB;   // 2304

typedef short bf16x8 __attribute__((ext_vector_type(8)));
typedef float f32x4  __attribute__((ext_vector_type(4)));

// f32 -> bf16 round-to-nearest-even (data is finite, no NaN handling needed)
__device__ inline unsigned short f2bf(float x) {
  unsigned u = __float_as_uint(x);
  unsigned r = u + 0x7fffu + ((u >> 16) & 1u);
  return (unsigned short)(r >> 16);
}
__device__ inline float bf2f(unsigned short h) {
  return __uint_as_float(((unsigned)h) << 16);
}

// ---------------------------------------------------------------------------
// fp32 NT-GEMM (kept for the output projection): C = A @ B^T + bias
// ---------------------------------------------------------------------------
constexpr int BM = 128, BN = 128, BK = 16;

__global__ __launch_bounds__(256) void gemm_nt_f32(
    const float* __restrict__ A, const float* __restrict__ Bm,
    const float* __restrict__ bias, float* __restrict__ C,
    int M, int N, int K)
{
  __shared__ __align__(16) float As[BK][BM + 4];
  __shared__ __align__(16) float Bs[BK][BN + 4];

  const int tid  = threadIdx.x;
  const int brow = blockIdx.x * BM;
  const int bcol = blockIdx.y * BN;
  const int tr   = (tid >> 4) << 3;
  const int tc   = (tid & 15) << 3;

  float acc[8][8] = {};

  for (int k0 = 0; k0 < K; k0 += BK) {
#pragma unroll
    for (int i = 0; i < 8; ++i) {
      int idx = tid + (i << 8);
      int kk  = idx & (BK - 1);
      int r   = idx >> 4;
      As[kk][r] = A [(size_t)(brow + r) * K + k0 + kk];
      Bs[kk][r] = Bm[(size_t)(bcol + r) * K + k0 + kk];
    }
    __syncthreads();
#pragma unroll
    for (int kk = 0; kk < BK; ++kk) {
      float a[8], b[8];
#pragma unroll
      for (int i = 0; i < 8; ++i) a[i] = As[kk][tr + i];
#pragma unroll
      for (int j = 0; j < 8; ++j) b[j] = Bs[kk][tc + j];
#pragma unroll
      for (int i = 0; i < 8; ++i)
#pragma unroll
        for (int j = 0; j < 8; ++j)
          acc[i][j] += a[i] * b[j];
    }
    __syncthreads();
  }

#pragma unroll
  for (int i = 0; i < 8; ++i) {
    size_t row = (size_t)(brow + tr + i) * N + bcol + tc;
#pragma unroll
    for (int j = 0; j < 8; j += 4) {
      float4 v;
      v.x = acc[i][j + 0] + bias[bcol + tc + j + 0];
      v.y = acc[i][j + 1] + bias[bcol + tc + j + 1];
      v.z = acc[i][j + 2] + bias[bcol + tc + j + 2];
      v.w = acc[i][j + 3] + bias[bcol + tc + j + 3];
      *reinterpret_cast<float4*>(&C[row + j]) = v;
    }
  }
}

// ---------------------------------------------------------------------------
// QKV projection: fp32 compute, epilogue emits split-bf16 planes (hi + lo).
// Q columns (col < 768) are pre-scaled by 1/sqrt(Dk) = 0.125 (exact pow2).
// ---------------------------------------------------------------------------
__global__ __launch_bounds__(256) void gemm_qkv_split(
    const float* __restrict__ A, const float* __restrict__ Bm,
    unsigned short* __restrict__ Chi, unsigned short* __restrict__ Clo,
    int M, int N, int K)
{
  __shared__ __align__(16) float As[BK][BM + 4];
  __shared__ __align__(16) float Bs[BK][BN + 4];

  const int tid  = threadIdx.x;
  const int brow = blockIdx.x * BM;
  const int bcol = blockIdx.y * BN;
  const int tr   = (tid >> 4) << 3;
  const int tc   = (tid & 15) << 3;

  float acc[8][8] = {};

  for (int k0 = 0; k0 < K; k0 += BK) {
#pragma unroll
    for (int i = 0; i < 8; ++i) {
      int idx = tid + (i << 8);
      int kk  = idx & (BK - 1);
      int r   = idx >> 4;
      As[kk][r] = A [(size_t)(brow + r) * K + k0 + kk];
      Bs[kk][r] = Bm[(size_t)(bcol + r) * K + k0 + kk];
    }
    __syncthreads();
#pragma unroll
    for (int kk = 0; kk < BK; ++kk) {
      float a[8], b[8];
#pragma unroll
      for (int i = 0; i < 8; ++i) a[i] = As[kk][tr + i];
#pragma unroll
      for (int j = 0; j < 8; ++j) b[j] = Bs[kk][tc + j];
#pragma unroll
      for (int i = 0; i < 8; ++i)
#pragma unroll
        for (int j = 0; j < 8; ++j)
          acc[i][j] += a[i] * b[j];
    }
    __syncthreads();
  }

  const float qscale = (bcol < EMB) ? 0.125f : 1.0f;  // whole block uniform
#pragma unroll
  for (int i = 0; i < 8; ++i) {
    size_t row = (size_t)(brow + tr + i) * N + bcol + tc;
    ushort4 h4, l4;
#pragma unroll
    for (int j = 0; j < 8; ++j) {
      float c = acc[i][j] * qscale;
      unsigned short hi = f2bf(c);
      unsigned short lo = f2bf(c - bf2f(hi));
      ((unsigned short*)&h4)[j & 3] = hi;
      ((unsigned short*)&l4)[j & 3] = lo;
      if ((j & 3) == 3) {
        *reinterpret_cast<ushort4*>(&Chi[row + (j & 4)]) = h4;
        *reinterpret_cast<ushort4*>(&Clo[row + (j & 4)]) = l4;
      }
    }
  }
}

// ---------------------------------------------------------------------------
// Flash attention, split-bf16 MFMA (16x16x32).
// Block = 256 threads = 4 waves; wave w owns q rows [q0+16w, q0+16w+16).
// One head per blockIdx.y. KV tile = 64. Full hi/lo split on QK^T and PV.
//
// LDS bank design (all wave-access patterns land uniform on the 32 banks):
//   Ks[t][72]  bf16  (stride 72 el = 144 B ≡ 4 dw mod 32 -> quad=(t+g)%8)
//   Vt[d][68]  u32   hi|lo interleaved, transposed (d-major)
//   Ps[w][q][68] u32 hi|lo interleaved, per-wave P tile
// ---------------------------------------------------------------------------
constexpr int KS_STR = 72;  // ushort units
constexpr int VT_STR = 68;  // u32 units
constexpr int PS_STR = 68;  // u32 units

__device__ inline void unpack_hl(uint4 r0, uint4 r1, bf16x8& h, bf16x8& l) {
  union { unsigned u[4]; bf16x8 v; } H, L;
  H.u[0] = (r0.x & 0xffffu) | (r0.y << 16);
  H.u[1] = (r0.z & 0xffffu) | (r0.w << 16);
  H.u[2] = (r1.x & 0xffffu) | (r1.y << 16);
  H.u[3] = (r1.z & 0xffffu) | (r1.w << 16);
  L.u[0] = (r0.x >> 16) | (r0.y & 0xffff0000u);
  L.u[1] = (r0.z >> 16) | (r0.w & 0xffff0000u);
  L.u[2] = (r1.x >> 16) | (r1.y & 0xffff0000u);
  L.u[3] = (r1.z >> 16) | (r1.w & 0xffff0000u);
  h = H.v; l = L.v;
}

__global__ __launch_bounds__(256) void flash_attn_mfma(
    const unsigned short* __restrict__ qkv_hi,
    const unsigned short* __restrict__ qkv_lo,
    float* __restrict__ attn_out)
{
  __shared__ __align__(16) unsigned short Ksh[64 * KS_STR];
  __shared__ __align__(16) unsigned short Ksl[64 * KS_STR];
  __shared__ __align__(16) unsigned       Vt [64 * VT_STR];
  __shared__ __align__(16) unsigned       Ps [4][16 * PS_STR];

  const int tid = threadIdx.x;
  const int w   = tid >> 6;
  const int l   = tid & 63;
  const int lg  = l >> 4;    // 0..3
  const int lr  = l & 15;    // 0..15
  const int q0  = blockIdx.x * 64;
  const int h   = blockIdx.y;

  // ---- hoist Q fragments (A-frag: row=lr, k=d=lg*8+j+32*ks), pre-scaled ----
  bf16x8 qfh[2], qfl[2];
  {
    const size_t qrow = (size_t)(q0 + w * 16 + lr) * QKV_DIM + h * DK;
#pragma unroll
    for (int ks = 0; ks < 2; ++ks) {
      qfh[ks] = *reinterpret_cast<const bf16x8*>(qkv_hi + qrow + ks * 32 + lg * 8);
      qfl[ks] = *reinterpret_cast<const bf16x8*>(qkv_lo + qrow + ks * 32 + lg * 8);
    }
  }

  f32x4 acc[4] = {};           // acc[dt]: row=lg*4+r, col d=dt*16+lr
  float m[4] = {-1e30f, -1e30f, -1e30f, -1e30f};
  float lsum[4] = {};

  // V staging role: thread covers d=g*8..g*8+7 for t-pair {2*tp, 2*tp+1}
  const int vg  = tid & 7;
  const int vtp = tid >> 3;    // 0..31

  for (int t0 = 0; t0 < S_LEN; t0 += 64) {
    // ---------------- stage K (separate hi/lo planes) ----------------
#pragma unroll
    for (int c = 0; c < 4; ++c) {
      int gidx = tid + (c << 8);          // 0..1023
      int comp = gidx >> 9;
      int rem  = gidx & 511;
      int t    = rem >> 3;
      int g    = rem & 7;
      const unsigned short* src =
          (comp ? qkv_lo : qkv_hi) + (size_t)(t0 + t) * QKV_DIM + EMB + h * DK + g * 8;
      uint4 v = *reinterpret_cast<const uint4*>(src);
      unsigned short* dst = (comp ? Ksl : Ksh) + t * KS_STR + g * 8;
      *reinterpret_cast<uint4*>(dst) = v;
    }
    // ---------------- stage V transposed, hi|lo interleaved ----------------
    {
      const size_t base = (size_t)(t0 + vtp * 2) * QKV_DIM + 2 * EMB + h * DK + vg * 8;
      uint4 h0 = *reinterpret_cast<const uint4*>(qkv_hi + base);
      uint4 h1 = *reinterpret_cast<const uint4*>(qkv_hi + base + QKV_DIM);
      uint4 l0 = *reinterpret_cast<const uint4*>(qkv_lo + base);
      uint4 l1 = *reinterpret_cast<const uint4*>(qkv_lo + base + QKV_DIM);
      const unsigned* h0u = (const unsigned*)&h0;
      const unsigned* h1u = (const unsigned*)&h1;
      const unsigned* l0u = (const unsigned*)&l0;
      const unsigned* l1u = (const unsigned*)&l1;
#pragma unroll
      for (int j = 0; j < 8; ++j) {
        unsigned he0 = (j & 1) ? (h0u[j >> 1] >> 16) : (h0u[j >> 1] & 0xffffu);
        unsigned le0 = (j & 1) ? (l0u[j >> 1] >> 16) : (l0u[j >> 1] & 0xffffu);
        unsigned he1 = (j & 1) ? (h1u[j >> 1] >> 16) : (h1u[j >> 1] & 0xffffu);
        unsigned le1 = (j & 1) ? (l1u[j >> 1] >> 16) : (l1u[j >> 1] & 0xffffu);
        uint2 pair;
        pair.x = he0 | (le0 << 16);
        pair.y = he1 | (le1 << 16);
        *reinterpret_cast<uint2*>(&Vt[(vg * 8 + j) * VT_STR + vtp * 2]) = pair;
      }
    }
    __syncthreads();

    // ---------------- QK^T: sc[tt] rows=lg*4+r, cols=tt*16+lr ----------------
    f32x4 sc[4];
#pragma unroll
    for (int tt = 0; tt < 4; ++tt) {
      f32x4 s = {};
#pragma unroll
      for (int ks = 0; ks < 2; ++ks) {
        int off = (tt * 16 + lr) * KS_STR + ks * 32 + lg * 8;
        bf16x8 kh = *reinterpret_cast<const bf16x8*>(&Ksh[off]);
        bf16x8 kl = *reinterpret_cast<const bf16x8*>(&Ksl[off]);
        s = __builtin_amdgcn_mfma_f32_16x16x32_bf16(qfh[ks], kh, s, 0, 0, 0);
        s = __builtin_amdgcn_mfma_f32_16x16x32_bf16(qfh[ks], kl, s, 0, 0, 0);
        s = __builtin_amdgcn_mfma_f32_16x16x32_bf16(qfl[ks], kh, s, 0, 0, 0);
      }
      sc[tt] = s;
    }

    // ---------------- online softmax (rows lg*4+r; reduce over lr lanes) ----
    float mn[4], scl[4], sum[4];
#pragma unroll
    for (int r = 0; r < 4; ++r) {
      float mx = fmaxf(fmaxf(sc[0][r], sc[1][r]), fmaxf(sc[2][r], sc[3][r]));
      mx = fmaxf(mx, __shfl_xor(mx, 1));
      mx = fmaxf(mx, __shfl_xor(mx, 2));
      mx = fmaxf(mx, __shfl_xor(mx, 4));
      mx = fmaxf(mx, __shfl_xor(mx, 8));
      mn[r]  = fmaxf(m[r], mx);
      scl[r] = __expf(m[r] - mn[r]);
      sum[r] = 0.0f;
    }
#pragma unroll
    for (int tt = 0; tt < 4; ++tt)
#pragma unroll
      for (int r = 0; r < 4; ++r) {
        float p = __expf(sc[tt][r] - mn[r]);
        sum[r] += p;
        sc[tt][r] = p;
      }
#pragma unroll
    for (int r = 0; r < 4; ++r) {
      sum[r] += __shfl_xor(sum[r], 1);
      sum[r] += __shfl_xor(sum[r], 2);
      sum[r] += __shfl_xor(sum[r], 4);
      sum[r] += __shfl_xor(sum[r], 8);
      lsum[r] = lsum[r] * scl[r] + sum[r];
      m[r] = mn[r];
#pragma unroll
      for (int dt = 0; dt < 4; ++dt) acc[dt][r] *= scl[r];
    }

    // ---------------- split P and write to per-wave LDS tile ----------------
#pragma unroll
    for (int tt = 0; tt < 4; ++tt)
#pragma unroll
      for (int r = 0; r < 4; ++r) {
        float p = sc[tt][r];
        unsigned short hi = f2bf(p);
        unsigned short lo = f2bf(p - bf2f(hi));
        Ps[w][(lg * 4 + r) * PS_STR + tt * 16 + lr] = (unsigned)hi | ((unsigned)lo << 16);
      }

    // ---------------- PV: acc[dt] += P @ V ----------------
#pragma unroll
    for (int ks = 0; ks < 2; ++ks) {
      int poff = lr * PS_STR + ks * 32 + lg * 8;
      uint4 a0 = *reinterpret_cast<const uint4*>(&Ps[w][poff]);
      uint4 a1 = *reinterpret_cast<const uint4*>(&Ps[w][poff + 4]);
      bf16x8 ph, pl;
      unpack_hl(a0, a1, ph, pl);
#pragma unroll
      for (int dt = 0; dt < 4; ++dt) {
        int voff = (dt * 16 + lr) * VT_STR + ks * 32 + lg * 8;
        uint4 b0 = *reinterpret_cast<const uint4*>(&Vt[voff]);
        uint4 b1 = *reinterpret_cast<const uint4*>(&Vt[voff + 4]);
        bf16x8 vh, vl;
        unpack_hl(b0, b1, vh, vl);
        acc[dt] = __builtin_amdgcn_mfma_f32_16x16x32_bf16(ph, vh, acc[dt], 0, 0, 0);
        acc[dt] = __builtin_amdgcn_mfma_f32_16x16x32_bf16(ph, vl, acc[dt], 0, 0, 0);
        acc[dt] = __builtin_amdgcn_mfma_f32_16x16x32_bf16(pl, vh, acc[dt], 0, 0, 0);
      }
    }
    __syncthreads();
  }

  // ---------------- epilogue: normalize and store ----------------
#pragma unroll
  for (int r = 0; r < 4; ++r) {
    float inv = 1.0f / lsum[r];
    size_t row = (size_t)(q0 + w * 16 + lg * 4 + r) * EMB + h * DK;
#pragma unroll
    for (int dt = 0; dt < 4; ++dt)
      attn_out[row + dt * 16 + lr] = acc[dt][r] * inv;
  }
}

// ---------------------------------------------------------------------------
extern "C" void kernel_launch(void* const* d_in, const int* in_sizes, int n_in,
                              void* d_out, int out_size, void* d_ws, size_t ws_size,
                              hipStream_t stream) {
  const float* x     = (const float*)d_in[0];
  const float* w_qkv = (const float*)d_in[1];
  const float* w_out = (const float*)d_in[2];
  const float* b_out = (const float*)d_in[3];
  float* out = (float*)d_out;

  unsigned short* qkv_hi = (unsigned short*)d_ws;                    // [4096][2304] bf16
  unsigned short* qkv_lo = qkv_hi + (size_t)S_LEN * QKV_DIM;         // [4096][2304] bf16
  float* attn_out = (float*)(qkv_lo + (size_t)S_LEN * QKV_DIM);     // [4096][768] f32

  dim3 blk(256);

  gemm_qkv_split<<<dim3(S_LEN / BM, QKV_DIM / BN), blk, 0, stream>>>(
      x, w_qkv, qkv_hi, qkv_lo, S_LEN, QKV_DIM, EMB);

  flash_attn_mfma<<<dim3(S_LEN / 64, NH), blk, 0, stream>>>(qkv_hi, qkv_lo, attn_out);

  gemm_nt_f32<<<dim3(S_LEN / BM, EMB / BN), blk, 0, stream>>>(
      attn_out, w_out, b_out, out, S_LEN, EMB, EMB);
}

// Round 3
// 608.729 us; speedup vs baseline: 2.0122x; 1.1814x over previous
//
#include <hip/hip_runtime.h>
#include <hip/hip_bf16.h>

constexpr int S_LEN   = 4096;
constexpr int EMB     = 768;
constexpr int NH      = 12;
constexpr int DK      = 64;
constexpr int QKV_DIM = 3 * EMB;   // 2304

typedef short bf16x8 __attribute__((ext_vector_type(8)));
typedef float f32x4  __attribute__((ext_vector_type(4)));

// f32 -> bf16 round-to-nearest-even
__device__ inline unsigned short f2bf(float x) {
  unsigned u = __float_as_uint(x);
  unsigned r = u + 0x7fffu + ((u >> 16) & 1u);
  return (unsigned short)(r >> 16);
}
__device__ inline float bf2f(unsigned short h) {
  return __uint_as_float(((unsigned)h) << 16);
}

// ---------------------------------------------------------------------------
// fp32 NT-GEMM (output projection): C = A @ B^T + bias   [unchanged from R2]
// ---------------------------------------------------------------------------
constexpr int BM = 128, BN = 128, BK = 16;

__global__ __launch_bounds__(256) void gemm_nt_f32(
    const float* __restrict__ A, const float* __restrict__ Bm,
    const float* __restrict__ bias, float* __restrict__ C,
    int M, int N, int K)
{
  __shared__ __align__(16) float As[BK][BM + 4];
  __shared__ __align__(16) float Bs[BK][BN + 4];

  const int tid  = threadIdx.x;
  const int brow = blockIdx.x * BM;
  const int bcol = blockIdx.y * BN;
  const int tr   = (tid >> 4) << 3;
  const int tc   = (tid & 15) << 3;

  float acc[8][8] = {};

  for (int k0 = 0; k0 < K; k0 += BK) {
#pragma unroll
    for (int i = 0; i < 8; ++i) {
      int idx = tid + (i << 8);
      int kk  = idx & (BK - 1);
      int r   = idx >> 4;
      As[kk][r] = A [(size_t)(brow + r) * K + k0 + kk];
      Bs[kk][r] = Bm[(size_t)(bcol + r) * K + k0 + kk];
    }
    __syncthreads();
#pragma unroll
    for (int kk = 0; kk < BK; ++kk) {
      float a[8], b[8];
#pragma unroll
      for (int i = 0; i < 8; ++i) a[i] = As[kk][tr + i];
#pragma unroll
      for (int j = 0; j < 8; ++j) b[j] = Bs[kk][tc + j];
#pragma unroll
      for (int i = 0; i < 8; ++i)
#pragma unroll
        for (int j = 0; j < 8; ++j)
          acc[i][j] += a[i] * b[j];
    }
    __syncthreads();
  }

#pragma unroll
  for (int i = 0; i < 8; ++i) {
    size_t row = (size_t)(brow + tr + i) * N + bcol + tc;
#pragma unroll
    for (int j = 0; j < 8; j += 4) {
      float4 v;
      v.x = acc[i][j + 0] + bias[bcol + tc + j + 0];
      v.y = acc[i][j + 1] + bias[bcol + tc + j + 1];
      v.z = acc[i][j + 2] + bias[bcol + tc + j + 2];
      v.w = acc[i][j + 3] + bias[bcol + tc + j + 3];
      *reinterpret_cast<float4*>(&C[row + j]) = v;
    }
  }
}

// ---------------------------------------------------------------------------
// QKV projection with split-bf16 epilogue (Q pre-scaled by 0.125) [unchanged]
// ---------------------------------------------------------------------------
__global__ __launch_bounds__(256) void gemm_qkv_split(
    const float* __restrict__ A, const float* __restrict__ Bm,
    unsigned short* __restrict__ Chi, unsigned short* __restrict__ Clo,
    int M, int N, int K)
{
  __shared__ __align__(16) float As[BK][BM + 4];
  __shared__ __align__(16) float Bs[BK][BN + 4];

  const int tid  = threadIdx.x;
  const int brow = blockIdx.x * BM;
  const int bcol = blockIdx.y * BN;
  const int tr   = (tid >> 4) << 3;
  const int tc   = (tid & 15) << 3;

  float acc[8][8] = {};

  for (int k0 = 0; k0 < K; k0 += BK) {
#pragma unroll
    for (int i = 0; i < 8; ++i) {
      int idx = tid + (i << 8);
      int kk  = idx & (BK - 1);
      int r   = idx >> 4;
      As[kk][r] = A [(size_t)(brow + r) * K + k0 + kk];
      Bs[kk][r] = Bm[(size_t)(bcol + r) * K + k0 + kk];
    }
    __syncthreads();
#pragma unroll
    for (int kk = 0; kk < BK; ++kk) {
      float a[8], b[8];
#pragma unroll
      for (int i = 0; i < 8; ++i) a[i] = As[kk][tr + i];
#pragma unroll
      for (int j = 0; j < 8; ++j) b[j] = Bs[kk][tc + j];
#pragma unroll
      for (int i = 0; i < 8; ++i)
#pragma unroll
        for (int j = 0; j < 8; ++j)
          acc[i][j] += a[i] * b[j];
    }
    __syncthreads();
  }

  const float qscale = (bcol < EMB) ? 0.125f : 1.0f;
#pragma unroll
  for (int i = 0; i < 8; ++i) {
    size_t row = (size_t)(brow + tr + i) * N + bcol + tc;
    ushort4 h4, l4;
#pragma unroll
    for (int j = 0; j < 8; ++j) {
      float c = acc[i][j] * qscale;
      unsigned short hi = f2bf(c);
      unsigned short lo = f2bf(c - bf2f(hi));
      ((unsigned short*)&h4)[j & 3] = hi;
      ((unsigned short*)&l4)[j & 3] = lo;
      if ((j & 3) == 3) {
        *reinterpret_cast<ushort4*>(&Chi[row + (j & 4)]) = h4;
        *reinterpret_cast<ushort4*>(&Clo[row + (j & 4)]) = l4;
      }
    }
  }
}

// ---------------------------------------------------------------------------
// Flash attention v3: swapped QK^T (A=K, B=Q), per-lane softmax, separate
// hi/lo LDS planes, XOR-swizzled LDS, 2 q-frags/wave (q-tile 128/block).
//
// All LDS rows are 64 bf16 = 128 B; 16B slot s swizzled to s ^ (row & 7).
// LDS: K 16KB + V 16KB + P 32KB = 64KB -> 2 blocks/CU.
// ---------------------------------------------------------------------------
__device__ inline int swz16(int row, int s) {          // ushort index, s=0..7
  return row * 64 + (((s) ^ (row & 7)) << 3);
}
__device__ inline int swz32(int row, int p) {          // u32 index, p=0..31
  return row * 32 + (((((p) >> 2) ^ (row & 7)) << 2) | ((p) & 3));
}

__global__ __launch_bounds__(256, 2) void flash_attn_mfma(
    const unsigned short* __restrict__ qkv_hi,
    const unsigned short* __restrict__ qkv_lo,
    float* __restrict__ attn_out)
{
  __shared__ __align__(16) unsigned short KsH[64 * 64];
  __shared__ __align__(16) unsigned short KsL[64 * 64];
  __shared__ __align__(16) unsigned short VtH[64 * 64];
  __shared__ __align__(16) unsigned short VtL[64 * 64];
  __shared__ __align__(16) unsigned short PsH[4][32 * 64];
  __shared__ __align__(16) unsigned short PsL[4][32 * 64];

  const int tid = threadIdx.x;
  const int w   = tid >> 6;
  const int l   = tid & 63;
  const int lg  = l >> 4;       // 0..3
  const int lr  = l & 15;       // 0..15

  // bijective XCD swizzle: 384 blocks = 8 XCDs x 48
  const int bid = blockIdx.x;
  const int sbid = (bid & 7) * 48 + (bid >> 3);
  const int h  = sbid >> 5;          // head 0..11
  const int qb = (sbid & 31) * 128;  // q-tile base

  unsigned* PwH   = (unsigned*)PsH[w];
  unsigned* PwL   = (unsigned*)PsL[w];
  unsigned* VtH32 = (unsigned*)VtH;
  unsigned* VtL32 = (unsigned*)VtL;

  // ---- Q fragments (used as MFMA B-operand: col=lr -> q, k=lg*8+j+32ks) ----
  bf16x8 qh[2][2], ql[2][2];
#pragma unroll
  for (int qf = 0; qf < 2; ++qf)
#pragma unroll
    for (int ks = 0; ks < 2; ++ks) {
      size_t off = (size_t)(qb + w * 32 + qf * 16 + lr) * QKV_DIM + h * DK + ks * 32 + lg * 8;
      qh[qf][ks] = *reinterpret_cast<const bf16x8*>(qkv_hi + off);
      ql[qf][ks] = *reinterpret_cast<const bf16x8*>(qkv_lo + off);
    }

  float m[2]  = {-1e30f, -1e30f};
  float ls[2] = {0.0f, 0.0f};
  f32x4 acc[2][4] = {};

  const int vg  = tid & 7;   // d-slot for V staging
  const int vtp = tid >> 3;  // t-pair 0..31

  for (int t0 = 0; t0 < S_LEN; t0 += 64) {
    // ---------------- stage K (hi/lo planes, swizzled) ----------------
#pragma unroll
    for (int c = 0; c < 2; ++c) {
      int idx = tid + (c << 8);       // 0..511
      int t = idx >> 3, g = idx & 7;
      size_t src = (size_t)(t0 + t) * QKV_DIM + EMB + h * DK + g * 8;
      *reinterpret_cast<uint4*>(&KsH[swz16(t, g)]) =
          *reinterpret_cast<const uint4*>(qkv_hi + src);
      *reinterpret_cast<uint4*>(&KsL[swz16(t, g)]) =
          *reinterpret_cast<const uint4*>(qkv_lo + src);
    }
    // ---------------- stage V transposed (hi/lo planes, swizzled) ----------
    {
      size_t src = (size_t)(t0 + 2 * vtp) * QKV_DIM + 2 * EMB + h * DK + vg * 8;
      uint4 h0 = *reinterpret_cast<const uint4*>(qkv_hi + src);
      uint4 h1 = *reinterpret_cast<const uint4*>(qkv_hi + src + QKV_DIM);
      uint4 l0 = *reinterpret_cast<const uint4*>(qkv_lo + src);
      uint4 l1 = *reinterpret_cast<const uint4*>(qkv_lo + src + QKV_DIM);
      const unsigned* a0 = reinterpret_cast<const unsigned*>(&h0);
      const unsigned* a1 = reinterpret_cast<const unsigned*>(&h1);
      const unsigned* b0 = reinterpret_cast<const unsigned*>(&l0);
      const unsigned* b1 = reinterpret_cast<const unsigned*>(&l1);
#pragma unroll
      for (int j = 0; j < 8; ++j) {
        int d = vg * 8 + j;
        unsigned ph, pl;
        if (j & 1) {
          ph = (a0[j >> 1] >> 16) | (a1[j >> 1] & 0xffff0000u);
          pl = (b0[j >> 1] >> 16) | (b1[j >> 1] & 0xffff0000u);
        } else {
          ph = (a0[j >> 1] & 0xffffu) | (a1[j >> 1] << 16);
          pl = (b0[j >> 1] & 0xffffu) | (b1[j >> 1] << 16);
        }
        VtH32[swz32(d, vtp)] = ph;
        VtL32[swz32(d, vtp)] = pl;
      }
    }
    __syncthreads();

    // ---------------- QK^T (A=K rows=t, B=Q cols=q) ----------------
    f32x4 sc[2][4] = {};
#pragma unroll
    for (int tt = 0; tt < 4; ++tt)
#pragma unroll
      for (int ks = 0; ks < 2; ++ks) {
        bf16x8 kh = *reinterpret_cast<const bf16x8*>(&KsH[swz16(tt * 16 + lr, 4 * ks + lg)]);
        bf16x8 kl = *reinterpret_cast<const bf16x8*>(&KsL[swz16(tt * 16 + lr, 4 * ks + lg)]);
#pragma unroll
        for (int qf = 0; qf < 2; ++qf) {
          f32x4 s = sc[qf][tt];
          s = __builtin_amdgcn_mfma_f32_16x16x32_bf16(kh, qh[qf][ks], s, 0, 0, 0);
          s = __builtin_amdgcn_mfma_f32_16x16x32_bf16(kl, qh[qf][ks], s, 0, 0, 0);
          s = __builtin_amdgcn_mfma_f32_16x16x32_bf16(kh, ql[qf][ks], s, 0, 0, 0);
          sc[qf][tt] = s;
        }
      }

    // ---------------- per-lane online softmax (q = own lr) ----------------
    float scl[2];
#pragma unroll
    for (int qf = 0; qf < 2; ++qf) {
      float mx = sc[qf][0][0];
#pragma unroll
      for (int tt = 0; tt < 4; ++tt)
#pragma unroll
        for (int r = 0; r < 4; ++r) mx = fmaxf(mx, sc[qf][tt][r]);
      mx = fmaxf(mx, __shfl_xor(mx, 16));
      mx = fmaxf(mx, __shfl_xor(mx, 32));
      float mn = fmaxf(m[qf], mx);
      scl[qf] = __expf(m[qf] - mn);
      float sum = 0.0f;
#pragma unroll
      for (int tt = 0; tt < 4; ++tt)
#pragma unroll
        for (int r = 0; r < 4; ++r) {
          float p = __expf(sc[qf][tt][r] - mn);
          sc[qf][tt][r] = p;
          sum += p;
        }
      sum += __shfl_xor(sum, 16);
      sum += __shfl_xor(sum, 32);
      ls[qf] = ls[qf] * scl[qf] + sum;
      m[qf] = mn;
    }

    // rescale acc (acc row q = qf*16 + 4*lg + r; scl lives at lane lr==4*lg+r)
#pragma unroll
    for (int qf = 0; qf < 2; ++qf)
#pragma unroll
      for (int r = 0; r < 4; ++r) {
        float s_r = __shfl(scl[qf], 20 * lg + r, 64);
#pragma unroll
        for (int dt = 0; dt < 4; ++dt) acc[qf][dt][r] *= s_r;
      }

    // ---------------- P -> split bf16, store pairs to per-wave LDS ---------
#pragma unroll
    for (int qf = 0; qf < 2; ++qf) {
      int qrow = qf * 16 + lr;
#pragma unroll
      for (int tt = 0; tt < 4; ++tt)
#pragma unroll
        for (int pr = 0; pr < 2; ++pr) {
          float p0 = sc[qf][tt][2 * pr + 0];
          float p1 = sc[qf][tt][2 * pr + 1];
          __hip_bfloat162 hb = __float22bfloat162_rn(make_float2(p0, p1));
          float2 hf = __bfloat1622float2(hb);
          __hip_bfloat162 lb = __float22bfloat162_rn(make_float2(p0 - hf.x, p1 - hf.y));
          union { __hip_bfloat162 b; unsigned u; } ch, cl;
          ch.b = hb; cl.b = lb;
          int p = 8 * tt + 2 * lg + pr;   // u32 index of t-pair (t = 16tt+4lg+2pr)
          PwH[swz32(qrow, p)] = ch.u;
          PwL[swz32(qrow, p)] = cl.u;
        }
    }

    // ---------------- PV (A=P rows=q, B=V cols=d) ----------------
#pragma unroll
    for (int ks = 0; ks < 2; ++ks) {
      bf16x8 pah[2], pal[2];
#pragma unroll
      for (int qf = 0; qf < 2; ++qf) {
        pah[qf] = *reinterpret_cast<const bf16x8*>(&PsH[w][swz16(qf * 16 + lr, lg + 4 * ks)]);
        pal[qf] = *reinterpret_cast<const bf16x8*>(&PsL[w][swz16(qf * 16 + lr, lg + 4 * ks)]);
      }
#pragma unroll
      for (int dt = 0; dt < 4; ++dt) {
        bf16x8 vh = *reinterpret_cast<const bf16x8*>(&VtH[swz16(dt * 16 + lr, lg + 4 * ks)]);
        bf16x8 vl = *reinterpret_cast<const bf16x8*>(&VtL[swz16(dt * 16 + lr, lg + 4 * ks)]);
#pragma unroll
        for (int qf = 0; qf < 2; ++qf) {
          f32x4 a = acc[qf][dt];
          a = __builtin_amdgcn_mfma_f32_16x16x32_bf16(pah[qf], vh, a, 0, 0, 0);
          a = __builtin_amdgcn_mfma_f32_16x16x32_bf16(pah[qf], vl, a, 0, 0, 0);
          a = __builtin_amdgcn_mfma_f32_16x16x32_bf16(pal[qf], vh, a, 0, 0, 0);
          acc[qf][dt] = a;
        }
      }
    }
    __syncthreads();
  }

  // ---------------- epilogue: normalize + store ----------------
#pragma unroll
  for (int qf = 0; qf < 2; ++qf) {
    float inv = 1.0f / ls[qf];
#pragma unroll
    for (int r = 0; r < 4; ++r) {
      float inv_r = __shfl(inv, 20 * lg + r, 64);
      size_t row = (size_t)(qb + w * 32 + qf * 16 + 4 * lg + r) * EMB + h * DK;
#pragma unroll
      for (int dt = 0; dt < 4; ++dt)
        attn_out[row + dt * 16 + lr] = acc[qf][dt][r] * inv_r;
    }
  }
}

// ---------------------------------------------------------------------------
extern "C" void kernel_launch(void* const* d_in, const int* in_sizes, int n_in,
                              void* d_out, int out_size, void* d_ws, size_t ws_size,
                              hipStream_t stream) {
  const float* x     = (const float*)d_in[0];
  const float* w_qkv = (const float*)d_in[1];
  const float* w_out = (const float*)d_in[2];
  const float* b_out = (const float*)d_in[3];
  float* out = (float*)d_out;

  unsigned short* qkv_hi = (unsigned short*)d_ws;                 // [4096][2304] bf16
  unsigned short* qkv_lo = qkv_hi + (size_t)S_LEN * QKV_DIM;      // [4096][2304] bf16
  float* attn_out = (float*)(qkv_lo + (size_t)S_LEN * QKV_DIM);   // [4096][768] f32

  dim3 blk(256);

  gemm_qkv_split<<<dim3(S_LEN / BM, QKV_DIM / BN), blk, 0, stream>>>(
      x, w_qkv, qkv_hi, qkv_lo, S_LEN, QKV_DIM, EMB);

  flash_attn_mfma<<<dim3(384), blk, 0, stream>>>(qkv_hi, qkv_lo, attn_out);

  gemm_nt_f32<<<dim3(S_LEN / BM, EMB / BN), blk, 0, stream>>>(
      attn_out, w_out, b_out, out, S_LEN, EMB, EMB);
}

// Round 4
// 391.885 us; speedup vs baseline: 3.1257x; 1.5533x over previous
//
#include <hip/hip_runtime.h>
#include <hip/hip_bf16.h>

constexpr int S_LEN   = 4096;
constexpr int EMB     = 768;
constexpr int NH      = 12;
constexpr int DK      = 64;
constexpr int QKV_DIM = 3 * EMB;   // 2304

typedef short bf16x8 __attribute__((ext_vector_type(8)));
typedef float f32x4  __attribute__((ext_vector_type(4)));
typedef unsigned short u16;

// f32 -> bf16 round-to-nearest-even
__device__ inline u16 f2bf(float x) {
  unsigned u = __float_as_uint(x);
  unsigned r = u + 0x7fffu + ((u >> 16) & 1u);
  return (u16)(r >> 16);
}
__device__ inline float bf2f(u16 h) {
  return __uint_as_float(((unsigned)h) << 16);
}

__device__ inline void gld16(unsigned* lds, const unsigned* g) {
  __builtin_amdgcn_global_load_lds(
      (const __attribute__((address_space(1))) unsigned*)g,
      (__attribute__((address_space(3))) unsigned*)lds, 16, 0, 0);
}

// ---------------------------------------------------------------------------
// split fp32 -> bf16 hi/lo planes (vectorized, grid-stride)
// ---------------------------------------------------------------------------
__global__ __launch_bounds__(256) void split_f32(
    const float* __restrict__ src, u16* __restrict__ hi, u16* __restrict__ lo,
    int n4)
{
  for (int i = blockIdx.x * 256 + threadIdx.x; i < n4; i += gridDim.x * 256) {
    float4 v = reinterpret_cast<const float4*>(src)[i];
    ushort4 h, l;
    const float* vp = reinterpret_cast<const float*>(&v);
    u16* hp = reinterpret_cast<u16*>(&h);
    u16* lp = reinterpret_cast<u16*>(&l);
#pragma unroll
    for (int j = 0; j < 4; ++j) {
      u16 hb = f2bf(vp[j]);
      hp[j] = hb;
      lp[j] = f2bf(vp[j] - bf2f(hb));
    }
    reinterpret_cast<ushort4*>(hi)[i] = h;
    reinterpret_cast<ushort4*>(lo)[i] = l;
  }
}

// ---------------------------------------------------------------------------
// Split-bf16 NT-GEMM: C[M,N] = A[M,K] @ B[N,K]^T via Ah*Bh + Ah*Bl + Al*Bh.
// 128x128 tile, BK=32, 256 thr = 4 waves (2x2), each wave 64x64 (4x4 frags).
// Staging via global_load_lds width=16 into linear row-major LDS tiles.
// MODE 0: emit split bf16 hi/lo planes, cols < EMB scaled by 0.125 (QKV).
// MODE 1: emit fp32 + bias (output projection).
// ---------------------------------------------------------------------------
template<int MODE>
__global__ __launch_bounds__(256) void gemm_bf16_split(
    const u16* __restrict__ Ah, const u16* __restrict__ Al,
    const u16* __restrict__ Bh, const u16* __restrict__ Bl,
    const float* __restrict__ bias,
    u16* __restrict__ Chi, u16* __restrict__ Clo, float* __restrict__ Cf,
    int M, int N, int K)
{
  __shared__ __align__(16) u16 sAh[128 * 32];
  __shared__ __align__(16) u16 sAl[128 * 32];
  __shared__ __align__(16) u16 sBh[128 * 32];
  __shared__ __align__(16) u16 sBl[128 * 32];

  const int tid  = threadIdx.x;
  const int w    = tid >> 6;
  const int l    = tid & 63;
  const int lg   = l >> 4;
  const int lr   = l & 15;
  const int wr   = w >> 1;        // wave row 0..1
  const int wc   = w & 1;         // wave col 0..1
  const int brow = blockIdx.x * 128;
  const int bcol = blockIdx.y * 128;

  // staging role: instruction c covers rows [16c,16c+16); lane i: row 16c+(i>>2), k (i&3)*8
  const int srow = l >> 2;
  const int skc  = (l & 3) * 8;

  f32x4 acc[4][4] = {};

  for (int k0 = 0; k0 < K; k0 += 32) {
#pragma unroll
    for (int cc = 0; cc < 2; ++cc) {
      int c = w * 2 + cc;
      size_t arow = (size_t)(brow + c * 16 + srow) * K + k0 + skc;
      size_t brow_ = (size_t)(bcol + c * 16 + srow) * K + k0 + skc;
      gld16((unsigned*)(sAh + c * 512), (const unsigned*)(Ah + arow));
      gld16((unsigned*)(sAl + c * 512), (const unsigned*)(Al + arow));
      gld16((unsigned*)(sBh + c * 512), (const unsigned*)(Bh + brow_));
      gld16((unsigned*)(sBl + c * 512), (const unsigned*)(Bl + brow_));
    }
    __syncthreads();

    bf16x8 fah[4], fal[4], fbh[4], fbl[4];
#pragma unroll
    for (int i = 0; i < 4; ++i) {
      int aoff = (wr * 64 + i * 16 + lr) * 32 + lg * 8;
      int boff = (wc * 64 + i * 16 + lr) * 32 + lg * 8;
      fah[i] = *reinterpret_cast<const bf16x8*>(&sAh[aoff]);
      fal[i] = *reinterpret_cast<const bf16x8*>(&sAl[aoff]);
      fbh[i] = *reinterpret_cast<const bf16x8*>(&sBh[boff]);
      fbl[i] = *reinterpret_cast<const bf16x8*>(&sBl[boff]);
    }
#pragma unroll
    for (int mi = 0; mi < 4; ++mi)
#pragma unroll
      for (int ni = 0; ni < 4; ++ni) {
        f32x4 a = acc[mi][ni];
        a = __builtin_amdgcn_mfma_f32_16x16x32_bf16(fah[mi], fbh[ni], a, 0, 0, 0);
        a = __builtin_amdgcn_mfma_f32_16x16x32_bf16(fah[mi], fbl[ni], a, 0, 0, 0);
        a = __builtin_amdgcn_mfma_f32_16x16x32_bf16(fal[mi], fbh[ni], a, 0, 0, 0);
        acc[mi][ni] = a;
      }
    __syncthreads();
  }

  // epilogue: C row m = brow + wr*64 + mi*16 + 4*lg + r, col n = bcol + wc*64 + ni*16 + lr
  if (MODE == 0) {
    const float qscale = (bcol < EMB) ? 0.125f : 1.0f;   // 768 is 128-aligned
#pragma unroll
    for (int mi = 0; mi < 4; ++mi)
#pragma unroll
      for (int ni = 0; ni < 4; ++ni)
#pragma unroll
        for (int r = 0; r < 4; ++r) {
          size_t m = brow + wr * 64 + mi * 16 + 4 * lg + r;
          size_t n = bcol + wc * 64 + ni * 16 + lr;
          float c = acc[mi][ni][r] * qscale;
          u16 hb = f2bf(c);
          Chi[m * N + n] = hb;
          Clo[m * N + n] = f2bf(c - bf2f(hb));
        }
  } else {
#pragma unroll
    for (int mi = 0; mi < 4; ++mi)
#pragma unroll
      for (int ni = 0; ni < 4; ++ni)
#pragma unroll
        for (int r = 0; r < 4; ++r) {
          size_t m = brow + wr * 64 + mi * 16 + 4 * lg + r;
          size_t n = bcol + wc * 64 + ni * 16 + lr;
          Cf[m * N + n] = acc[mi][ni][r] + bias[n];
        }
  }
}

// ---------------------------------------------------------------------------
// Flash attention (identical to R3 except epilogue emits split bf16 planes).
// ---------------------------------------------------------------------------
__device__ inline int swz16(int row, int s) {          // ushort index, s=0..7
  return row * 64 + (((s) ^ (row & 7)) << 3);
}
__device__ inline int swz32(int row, int p) {          // u32 index, p=0..31
  return row * 32 + (((((p) >> 2) ^ (row & 7)) << 2) | ((p) & 3));
}

__global__ __launch_bounds__(256, 2) void flash_attn_mfma(
    const u16* __restrict__ qkv_hi,
    const u16* __restrict__ qkv_lo,
    u16* __restrict__ ao_hi, u16* __restrict__ ao_lo)
{
  __shared__ __align__(16) u16 KsH[64 * 64];
  __shared__ __align__(16) u16 KsL[64 * 64];
  __shared__ __align__(16) u16 VtH[64 * 64];
  __shared__ __align__(16) u16 VtL[64 * 64];
  __shared__ __align__(16) u16 PsH[4][32 * 64];
  __shared__ __align__(16) u16 PsL[4][32 * 64];

  const int tid = threadIdx.x;
  const int w   = tid >> 6;
  const int l   = tid & 63;
  const int lg  = l >> 4;
  const int lr  = l & 15;

  const int bid = blockIdx.x;
  const int sbid = (bid & 7) * 48 + (bid >> 3);
  const int h  = sbid >> 5;
  const int qb = (sbid & 31) * 128;

  unsigned* PwH   = (unsigned*)PsH[w];
  unsigned* PwL   = (unsigned*)PsL[w];
  unsigned* VtH32 = (unsigned*)VtH;
  unsigned* VtL32 = (unsigned*)VtL;

  bf16x8 qh[2][2], ql[2][2];
#pragma unroll
  for (int qf = 0; qf < 2; ++qf)
#pragma unroll
    for (int ks = 0; ks < 2; ++ks) {
      size_t off = (size_t)(qb + w * 32 + qf * 16 + lr) * QKV_DIM + h * DK + ks * 32 + lg * 8;
      qh[qf][ks] = *reinterpret_cast<const bf16x8*>(qkv_hi + off);
      ql[qf][ks] = *reinterpret_cast<const bf16x8*>(qkv_lo + off);
    }

  float m[2]  = {-1e30f, -1e30f};
  float ls[2] = {0.0f, 0.0f};
  f32x4 acc[2][4] = {};

  const int vg  = tid & 7;
  const int vtp = tid >> 3;

  for (int t0 = 0; t0 < S_LEN; t0 += 64) {
#pragma unroll
    for (int c = 0; c < 2; ++c) {
      int idx = tid + (c << 8);
      int t = idx >> 3, g = idx & 7;
      size_t src = (size_t)(t0 + t) * QKV_DIM + EMB + h * DK + g * 8;
      *reinterpret_cast<uint4*>(&KsH[swz16(t, g)]) =
          *reinterpret_cast<const uint4*>(qkv_hi + src);
      *reinterpret_cast<uint4*>(&KsL[swz16(t, g)]) =
          *reinterpret_cast<const uint4*>(qkv_lo + src);
    }
    {
      size_t src = (size_t)(t0 + 2 * vtp) * QKV_DIM + 2 * EMB + h * DK + vg * 8;
      uint4 h0 = *reinterpret_cast<const uint4*>(qkv_hi + src);
      uint4 h1 = *reinterpret_cast<const uint4*>(qkv_hi + src + QKV_DIM);
      uint4 l0 = *reinterpret_cast<const uint4*>(qkv_lo + src);
      uint4 l1 = *reinterpret_cast<const uint4*>(qkv_lo + src + QKV_DIM);
      const unsigned* a0 = reinterpret_cast<const unsigned*>(&h0);
      const unsigned* a1 = reinterpret_cast<const unsigned*>(&h1);
      const unsigned* b0 = reinterpret_cast<const unsigned*>(&l0);
      const unsigned* b1 = reinterpret_cast<const unsigned*>(&l1);
#pragma unroll
      for (int j = 0; j < 8; ++j) {
        int d = vg * 8 + j;
        unsigned ph, pl;
        if (j & 1) {
          ph = (a0[j >> 1] >> 16) | (a1[j >> 1] & 0xffff0000u);
          pl = (b0[j >> 1] >> 16) | (b1[j >> 1] & 0xffff0000u);
        } else {
          ph = (a0[j >> 1] & 0xffffu) | (a1[j >> 1] << 16);
          pl = (b0[j >> 1] & 0xffffu) | (b1[j >> 1] << 16);
        }
        VtH32[swz32(d, vtp)] = ph;
        VtL32[swz32(d, vtp)] = pl;
      }
    }
    __syncthreads();

    f32x4 sc[2][4] = {};
#pragma unroll
    for (int tt = 0; tt < 4; ++tt)
#pragma unroll
      for (int ks = 0; ks < 2; ++ks) {
        bf16x8 kh = *reinterpret_cast<const bf16x8*>(&KsH[swz16(tt * 16 + lr, 4 * ks + lg)]);
        bf16x8 kl = *reinterpret_cast<const bf16x8*>(&KsL[swz16(tt * 16 + lr, 4 * ks + lg)]);
#pragma unroll
        for (int qf = 0; qf < 2; ++qf) {
          f32x4 s = sc[qf][tt];
          s = __builtin_amdgcn_mfma_f32_16x16x32_bf16(kh, qh[qf][ks], s, 0, 0, 0);
          s = __builtin_amdgcn_mfma_f32_16x16x32_bf16(kl, qh[qf][ks], s, 0, 0, 0);
          s = __builtin_amdgcn_mfma_f32_16x16x32_bf16(kh, ql[qf][ks], s, 0, 0, 0);
          sc[qf][tt] = s;
        }
      }

    float scl[2];
#pragma unroll
    for (int qf = 0; qf < 2; ++qf) {
      float mx = sc[qf][0][0];
#pragma unroll
      for (int tt = 0; tt < 4; ++tt)
#pragma unroll
        for (int r = 0; r < 4; ++r) mx = fmaxf(mx, sc[qf][tt][r]);
      mx = fmaxf(mx, __shfl_xor(mx, 16));
      mx = fmaxf(mx, __shfl_xor(mx, 32));
      float mn = fmaxf(m[qf], mx);
      scl[qf] = __expf(m[qf] - mn);
      float sum = 0.0f;
#pragma unroll
      for (int tt = 0; tt < 4; ++tt)
#pragma unroll
        for (int r = 0; r < 4; ++r) {
          float p = __expf(sc[qf][tt][r] - mn);
          sc[qf][tt][r] = p;
          sum += p;
        }
      sum += __shfl_xor(sum, 16);
      sum += __shfl_xor(sum, 32);
      ls[qf] = ls[qf] * scl[qf] + sum;
      m[qf] = mn;
    }

#pragma unroll
    for (int qf = 0; qf < 2; ++qf)
#pragma unroll
      for (int r = 0; r < 4; ++r) {
        float s_r = __shfl(scl[qf], 20 * lg + r, 64);
#pragma unroll
        for (int dt = 0; dt < 4; ++dt) acc[qf][dt][r] *= s_r;
      }

#pragma unroll
    for (int qf = 0; qf < 2; ++qf) {
      int qrow = qf * 16 + lr;
#pragma unroll
      for (int tt = 0; tt < 4; ++tt)
#pragma unroll
        for (int pr = 0; pr < 2; ++pr) {
          float p0 = sc[qf][tt][2 * pr + 0];
          float p1 = sc[qf][tt][2 * pr + 1];
          __hip_bfloat162 hb = __float22bfloat162_rn(make_float2(p0, p1));
          float2 hf = __bfloat1622float2(hb);
          __hip_bfloat162 lb = __float22bfloat162_rn(make_float2(p0 - hf.x, p1 - hf.y));
          union { __hip_bfloat162 b; unsigned u; } ch, cl;
          ch.b = hb; cl.b = lb;
          int p = 8 * tt + 2 * lg + pr;
          PwH[swz32(qrow, p)] = ch.u;
          PwL[swz32(qrow, p)] = cl.u;
        }
    }

#pragma unroll
    for (int ks = 0; ks < 2; ++ks) {
      bf16x8 pah[2], pal[2];
#pragma unroll
      for (int qf = 0; qf < 2; ++qf) {
        pah[qf] = *reinterpret_cast<const bf16x8*>(&PsH[w][swz16(qf * 16 + lr, lg + 4 * ks)]);
        pal[qf] = *reinterpret_cast<const bf16x8*>(&PsL[w][swz16(qf * 16 + lr, lg + 4 * ks)]);
      }
#pragma unroll
      for (int dt = 0; dt < 4; ++dt) {
        bf16x8 vh = *reinterpret_cast<const bf16x8*>(&VtH[swz16(dt * 16 + lr, lg + 4 * ks)]);
        bf16x8 vl = *reinterpret_cast<const bf16x8*>(&VtL[swz16(dt * 16 + lr, lg + 4 * ks)]);
#pragma unroll
        for (int qf = 0; qf < 2; ++qf) {
          f32x4 a = acc[qf][dt];
          a = __builtin_amdgcn_mfma_f32_16x16x32_bf16(pah[qf], vh, a, 0, 0, 0);
          a = __builtin_amdgcn_mfma_f32_16x16x32_bf16(pah[qf], vl, a, 0, 0, 0);
          a = __builtin_amdgcn_mfma_f32_16x16x32_bf16(pal[qf], vh, a, 0, 0, 0);
          acc[qf][dt] = a;
        }
      }
    }
    __syncthreads();
  }

  // epilogue: normalize + store as split bf16 planes (input to out-proj GEMM)
#pragma unroll
  for (int qf = 0; qf < 2; ++qf) {
    float inv = 1.0f / ls[qf];
#pragma unroll
    for (int r = 0; r < 4; ++r) {
      float inv_r = __shfl(inv, 20 * lg + r, 64);
      size_t row = (size_t)(qb + w * 32 + qf * 16 + 4 * lg + r) * EMB + h * DK;
#pragma unroll
      for (int dt = 0; dt < 4; ++dt) {
        float o = acc[qf][dt][r] * inv_r;
        u16 hb = f2bf(o);
        ao_hi[row + dt * 16 + lr] = hb;
        ao_lo[row + dt * 16 + lr] = f2bf(o - bf2f(hb));
      }
    }
  }
}

// ---------------------------------------------------------------------------
extern "C" void kernel_launch(void* const* d_in, const int* in_sizes, int n_in,
                              void* d_out, int out_size, void* d_ws, size_t ws_size,
                              hipStream_t stream) {
  const float* x     = (const float*)d_in[0];
  const float* w_qkv = (const float*)d_in[1];
  const float* w_out = (const float*)d_in[2];
  const float* b_out = (const float*)d_in[3];
  float* out = (float*)d_out;

  constexpr size_t NX  = (size_t)S_LEN * EMB;        // 3145728
  constexpr size_t NWQ = (size_t)QKV_DIM * EMB;      // 1769472
  constexpr size_t NWO = (size_t)EMB * EMB;          // 589824
  constexpr size_t NQ  = (size_t)S_LEN * QKV_DIM;    // 9437184

  u16* xh   = (u16*)d_ws;
  u16* xl   = xh + NX;
  u16* wqh  = xl + NX;
  u16* wql  = wqh + NWQ;
  u16* woh  = wql + NWQ;
  u16* wol  = woh + NWO;
  u16* qkvh = wol + NWO;
  u16* qkvl = qkvh + NQ;
  u16* aoh  = xh;   // alias: x planes dead after QKV GEMM
  u16* aol  = xl;

  dim3 blk(256);

  split_f32<<<dim3(512), blk, 0, stream>>>(x,     xh,  xl,  (int)(NX / 4));
  split_f32<<<dim3(512), blk, 0, stream>>>(w_qkv, wqh, wql, (int)(NWQ / 4));
  split_f32<<<dim3(512), blk, 0, stream>>>(w_out, woh, wol, (int)(NWO / 4));

  // qkv = x @ w_qkv^T (split output, Q pre-scaled by 0.125)
  gemm_bf16_split<0><<<dim3(S_LEN / 128, QKV_DIM / 128), blk, 0, stream>>>(
      xh, xl, wqh, wql, nullptr, qkvh, qkvl, nullptr, S_LEN, QKV_DIM, EMB);

  // attention -> split planes
  flash_attn_mfma<<<dim3(384), blk, 0, stream>>>(qkvh, qkvl, aoh, aol);

  // out = attn @ w_out^T + b_out (fp32 output)
  gemm_bf16_split<1><<<dim3(S_LEN / 128, EMB / 128), blk, 0, stream>>>(
      aoh, aol, woh, wol, b_out, nullptr, nullptr, out, S_LEN, EMB, EMB);
}

// Round 5
// 220.028 us; speedup vs baseline: 5.5671x; 1.7811x over previous
//
#include <hip/hip_runtime.h>
#include <hip/hip_bf16.h>

constexpr int S_LEN   = 4096;
constexpr int EMB     = 768;
constexpr int NH      = 12;
constexpr int DK      = 64;
constexpr int QKV_DIM = 3 * EMB;   // 2304

typedef short bf16x8 __attribute__((ext_vector_type(8)));
typedef float f32x4  __attribute__((ext_vector_type(4)));
typedef unsigned short u16;

// f32 -> bf16 round-to-nearest-even
__device__ inline u16 f2bf(float x) {
  unsigned u = __float_as_uint(x);
  unsigned r = u + 0x7fffu + ((u >> 16) & 1u);
  return (u16)(r >> 16);
}
__device__ inline float bf2f(u16 h) {
  return __uint_as_float(((unsigned)h) << 16);
}

__device__ inline void gld16(unsigned* lds, const unsigned* g) {
  __builtin_amdgcn_global_load_lds(
      (const __attribute__((address_space(1))) unsigned*)g,
      (__attribute__((address_space(3))) unsigned*)lds, 16, 0, 0);
}

// ---------------------------------------------------------------------------
// fp32 -> bf16 cast (8 elems/thread, grid-stride)
// ---------------------------------------------------------------------------
__global__ __launch_bounds__(256) void cast_bf16(
    const float* __restrict__ src, u16* __restrict__ dst, int n8)
{
  for (int i = blockIdx.x * 256 + threadIdx.x; i < n8; i += gridDim.x * 256) {
    float4 a = reinterpret_cast<const float4*>(src)[2 * i + 0];
    float4 b = reinterpret_cast<const float4*>(src)[2 * i + 1];
    ushort4 h0, h1;
    const float* ap = reinterpret_cast<const float*>(&a);
    const float* bp = reinterpret_cast<const float*>(&b);
#pragma unroll
    for (int j = 0; j < 4; ++j) {
      reinterpret_cast<u16*>(&h0)[j] = f2bf(ap[j]);
      reinterpret_cast<u16*>(&h1)[j] = f2bf(bp[j]);
    }
    reinterpret_cast<ushort4*>(dst)[2 * i + 0] = h0;
    reinterpret_cast<ushort4*>(dst)[2 * i + 1] = h1;
  }
}

// ---------------------------------------------------------------------------
// bf16 NT-GEMM: C[M,N] = A[M,K] @ B[N,K]^T, fp32 accum.
// 128x128 tile, BK=64, 256 thr = 4 waves (2x2), wave = 64x64 (4x4 frags).
// Staging: global_load_lds w=16, LINEAR dest + pre-swizzled SOURCE; reads
// use matching XOR swizzle (slot ^ (row&7)) -> 2-way max (free).
// MODE 0: bf16 out, cols<EMB scaled 0.125 (QKV). MODE 1: fp32 + bias.
// ---------------------------------------------------------------------------
template<int MODE>
__global__ __launch_bounds__(256) void gemm_bf16_nt(
    const u16* __restrict__ A, const u16* __restrict__ B,
    const float* __restrict__ bias,
    u16* __restrict__ Cb, float* __restrict__ Cf,
    int M, int N, int K)
{
  __shared__ __align__(16) u16 sA[128 * 64];
  __shared__ __align__(16) u16 sB[128 * 64];

  const int tid  = threadIdx.x;
  const int w    = tid >> 6;
  const int l    = tid & 63;
  const int lg   = l >> 4;
  const int lr   = l & 15;
  const int wr   = w >> 1;
  const int wc   = w & 1;
  const int brow = blockIdx.x * 128;
  const int bcol = blockIdx.y * 128;

  // staging: instr c covers rows [8c, 8c+8); lane: row 8c+(l>>3), slot l&7
  const int srow = l >> 3;            // 0..7
  const int sslot = l & 7;            // 0..7

  f32x4 acc[4][4] = {};

  for (int k0 = 0; k0 < K; k0 += 64) {
#pragma unroll
    for (int cc = 0; cc < 4; ++cc) {
      int c = w * 4 + cc;             // 0..15
      int row = c * 8 + srow;
      int kswz = (sslot ^ (row & 7)) * 8;
      size_t aoff = (size_t)(brow + row) * K + k0 + kswz;
      size_t boff = (size_t)(bcol + row) * K + k0 + kswz;
      gld16((unsigned*)(sA + c * 512), (const unsigned*)(A + aoff));
      gld16((unsigned*)(sB + c * 512), (const unsigned*)(B + boff));
    }
    __syncthreads();

#pragma unroll
    for (int ks = 0; ks < 2; ++ks) {
      bf16x8 fa[4], fb[4];
#pragma unroll
      for (int i = 0; i < 4; ++i) {
        int arow = wr * 64 + i * 16 + lr;
        int brow_ = wc * 64 + i * 16 + lr;
        fa[i] = *reinterpret_cast<const bf16x8*>(
            &sA[arow * 64 + (((lg + 4 * ks) ^ (arow & 7)) << 3)]);
        fb[i] = *reinterpret_cast<const bf16x8*>(
            &sB[brow_ * 64 + (((lg + 4 * ks) ^ (brow_ & 7)) << 3)]);
      }
#pragma unroll
      for (int mi = 0; mi < 4; ++mi)
#pragma unroll
        for (int ni = 0; ni < 4; ++ni)
          acc[mi][ni] = __builtin_amdgcn_mfma_f32_16x16x32_bf16(
              fa[mi], fb[ni], acc[mi][ni], 0, 0, 0);
    }
    __syncthreads();
  }

  if (MODE == 0) {
    const float qscale = (bcol < EMB) ? 0.125f : 1.0f;
#pragma unroll
    for (int mi = 0; mi < 4; ++mi)
#pragma unroll
      for (int ni = 0; ni < 4; ++ni)
#pragma unroll
        for (int r = 0; r < 4; ++r) {
          size_t m = brow + wr * 64 + mi * 16 + 4 * lg + r;
          size_t n = bcol + wc * 64 + ni * 16 + lr;
          Cb[m * N + n] = f2bf(acc[mi][ni][r] * qscale);
        }
  } else {
#pragma unroll
    for (int mi = 0; mi < 4; ++mi)
#pragma unroll
      for (int ni = 0; ni < 4; ++ni)
#pragma unroll
        for (int r = 0; r < 4; ++r) {
          size_t m = brow + wr * 64 + mi * 16 + 4 * lg + r;
          size_t n = bcol + wc * 64 + ni * 16 + lr;
          Cf[m * N + n] = acc[mi][ni][r] + bias[n];
        }
  }
}

// ---------------------------------------------------------------------------
// Flash attention, all-bf16 core (fp32 softmax + accum).
// Block = 128 threads = 2 waves; q-tile 64 (wave w: rows w*32..w*32+32, qf=2).
// Grid 768 blocks = 12 heads x 64 q-tiles = exactly 3 blocks/CU.
// LDS: K 8KB + Vt 8KB + P 2x4KB = 24KB.
// ---------------------------------------------------------------------------
__device__ inline int swz16(int row, int s) {          // u16 idx; 16B slot s
  return row * 64 + (((s) ^ (row & 7)) << 3);
}
__device__ inline int swz32(int row, int p) {          // u32 idx; p=0..31
  return row * 32 + (((((p) >> 2) ^ (row & 7)) << 2) | ((p) & 3));
}

__global__ __launch_bounds__(128, 2) void flash_attn_bf16(
    const u16* __restrict__ qkv, u16* __restrict__ ao)
{
  __shared__ __align__(16) u16 Ks[64 * 64];
  __shared__ __align__(16) u16 Vt[64 * 64];
  __shared__ __align__(16) u16 Ps[2][32 * 64];

  const int tid = threadIdx.x;
  const int w   = tid >> 6;
  const int l   = tid & 63;
  const int lg  = l >> 4;
  const int lr  = l & 15;

  // XCD swizzle: 768 = 8 x 96
  const int bid  = blockIdx.x;
  const int sbid = (bid & 7) * 96 + (bid >> 3);
  const int h  = sbid >> 6;            // 0..11
  const int qb = (sbid & 63) * 64;     // q-tile base

  unsigned* Pw   = (unsigned*)Ps[w];
  unsigned* Vt32 = (unsigned*)Vt;

  // Q fragments (MFMA B-operand: col=lr -> q, k = d = ks*32 + lg*8 + j)
  bf16x8 qf_[2][2];
#pragma unroll
  for (int qf = 0; qf < 2; ++qf)
#pragma unroll
    for (int ks = 0; ks < 2; ++ks)
      qf_[qf][ks] = *reinterpret_cast<const bf16x8*>(
          qkv + (size_t)(qb + w * 32 + qf * 16 + lr) * QKV_DIM + h * DK + ks * 32 + lg * 8);

  float m[2]  = {-1e30f, -1e30f};
  float ls[2] = {0.0f, 0.0f};
  f32x4 acc[2][4] = {};

  const int tq  = tid >> 3;   // 0..15 (t-quad for V staging)
  const int vgs = tid & 7;    // d-slot

  for (int t0 = 0; t0 < S_LEN; t0 += 64) {
    // ---- stage K [t][d], swizzled rows ----
#pragma unroll
    for (int c = 0; c < 4; ++c) {
      int idx = tid + (c << 7);       // 0..511
      int t = idx >> 3, g = idx & 7;
      *reinterpret_cast<uint4*>(&Ks[swz16(t, g)]) =
          *reinterpret_cast<const uint4*>(
              qkv + (size_t)(t0 + t) * QKV_DIM + EMB + h * DK + g * 8);
    }
    // ---- stage V transposed Vt[d][t], b64 packed writes ----
    {
      size_t src = (size_t)(t0 + 4 * tq) * QKV_DIM + 2 * EMB + h * DK + vgs * 8;
      uint4 r0 = *reinterpret_cast<const uint4*>(qkv + src);
      uint4 r1 = *reinterpret_cast<const uint4*>(qkv + src + QKV_DIM);
      uint4 r2 = *reinterpret_cast<const uint4*>(qkv + src + 2 * QKV_DIM);
      uint4 r3 = *reinterpret_cast<const uint4*>(qkv + src + 3 * QKV_DIM);
      const u16* e0 = reinterpret_cast<const u16*>(&r0);
      const u16* e1 = reinterpret_cast<const u16*>(&r1);
      const u16* e2 = reinterpret_cast<const u16*>(&r2);
      const u16* e3 = reinterpret_cast<const u16*>(&r3);
#pragma unroll
      for (int j = 0; j < 8; ++j) {
        int d = vgs * 8 + j;
        uint2 pv;
        pv.x = (unsigned)e0[j] | ((unsigned)e1[j] << 16);
        pv.y = (unsigned)e2[j] | ((unsigned)e3[j] << 16);
        *reinterpret_cast<uint2*>(&Vt32[swz32(d, 2 * tq)]) = pv;
      }
    }
    __syncthreads();

    // ---- QK^T (A=K rows=t, B=Q cols=q): sc[qf][tt] ----
    f32x4 sc[2][4] = {};
#pragma unroll
    for (int tt = 0; tt < 4; ++tt)
#pragma unroll
      for (int ks = 0; ks < 2; ++ks) {
        bf16x8 kf = *reinterpret_cast<const bf16x8*>(&Ks[swz16(tt * 16 + lr, 4 * ks + lg)]);
#pragma unroll
        for (int qf = 0; qf < 2; ++qf)
          sc[qf][tt] = __builtin_amdgcn_mfma_f32_16x16x32_bf16(
              kf, qf_[qf][ks], sc[qf][tt], 0, 0, 0);
      }

    // ---- per-lane online softmax (own q = lr; reduce over lg via xor16/32) --
    float scl[2];
#pragma unroll
    for (int qf = 0; qf < 2; ++qf) {
      float mx = sc[qf][0][0];
#pragma unroll
      for (int tt = 0; tt < 4; ++tt)
#pragma unroll
        for (int r = 0; r < 4; ++r) mx = fmaxf(mx, sc[qf][tt][r]);
      mx = fmaxf(mx, __shfl_xor(mx, 16));
      mx = fmaxf(mx, __shfl_xor(mx, 32));
      float mn = fmaxf(m[qf], mx);
      scl[qf] = __expf(m[qf] - mn);
      float sum = 0.0f;
#pragma unroll
      for (int tt = 0; tt < 4; ++tt)
#pragma unroll
        for (int r = 0; r < 4; ++r) {
          float p = __expf(sc[qf][tt][r] - mn);
          sc[qf][tt][r] = p;
          sum += p;
        }
      sum += __shfl_xor(sum, 16);
      sum += __shfl_xor(sum, 32);
      ls[qf] = ls[qf] * scl[qf] + sum;
      m[qf] = mn;
    }

    // rescale acc (acc row q = 4lg+r; scl lives at any lane with lr = 4lg+r)
#pragma unroll
    for (int qf = 0; qf < 2; ++qf)
#pragma unroll
      for (int r = 0; r < 4; ++r) {
        float s_r = __shfl(scl[qf], 20 * lg + r, 64);
#pragma unroll
        for (int dt = 0; dt < 4; ++dt) acc[qf][dt][r] *= s_r;
      }

    // ---- P -> bf16 pairs into per-wave LDS ----
#pragma unroll
    for (int qf = 0; qf < 2; ++qf) {
      int qrow = qf * 16 + lr;
#pragma unroll
      for (int tt = 0; tt < 4; ++tt)
#pragma unroll
        for (int pr = 0; pr < 2; ++pr) {
          u16 b0 = f2bf(sc[qf][tt][2 * pr + 0]);
          u16 b1 = f2bf(sc[qf][tt][2 * pr + 1]);
          Pw[swz32(qrow, 8 * tt + 2 * lg + pr)] = (unsigned)b0 | ((unsigned)b1 << 16);
        }
    }

    // ---- PV: acc[qf][dt] += P @ V ----
#pragma unroll
    for (int ks = 0; ks < 2; ++ks) {
      bf16x8 pa[2];
#pragma unroll
      for (int qf = 0; qf < 2; ++qf)
        pa[qf] = *reinterpret_cast<const bf16x8*>(&Ps[w][swz16(qf * 16 + lr, 4 * ks + lg)]);
#pragma unroll
      for (int dt = 0; dt < 4; ++dt) {
        bf16x8 vf = *reinterpret_cast<const bf16x8*>(&Vt[swz16(dt * 16 + lr, 4 * ks + lg)]);
#pragma unroll
        for (int qf = 0; qf < 2; ++qf)
          acc[qf][dt] = __builtin_amdgcn_mfma_f32_16x16x32_bf16(
              pa[qf], vf, acc[qf][dt], 0, 0, 0);
      }
    }
    __syncthreads();
  }

  // ---- epilogue: normalize, store bf16 ----
#pragma unroll
  for (int qf = 0; qf < 2; ++qf) {
    float inv = 1.0f / ls[qf];
#pragma unroll
    for (int r = 0; r < 4; ++r) {
      float inv_r = __shfl(inv, 20 * lg + r, 64);
      size_t row = (size_t)(qb + w * 32 + qf * 16 + 4 * lg + r) * EMB + h * DK;
#pragma unroll
      for (int dt = 0; dt < 4; ++dt)
        ao[row + dt * 16 + lr] = f2bf(acc[qf][dt][r] * inv_r);
    }
  }
}

// ---------------------------------------------------------------------------
extern "C" void kernel_launch(void* const* d_in, const int* in_sizes, int n_in,
                              void* d_out, int out_size, void* d_ws, size_t ws_size,
                              hipStream_t stream) {
  const float* x     = (const float*)d_in[0];
  const float* w_qkv = (const float*)d_in[1];
  const float* w_out = (const float*)d_in[2];
  const float* b_out = (const float*)d_in[3];
  float* out = (float*)d_out;

  constexpr size_t NX  = (size_t)S_LEN * EMB;
  constexpr size_t NWQ = (size_t)QKV_DIM * EMB;
  constexpr size_t NWO = (size_t)EMB * EMB;
  constexpr size_t NQ  = (size_t)S_LEN * QKV_DIM;

  u16* xb   = (u16*)d_ws;
  u16* wqb  = xb + NX;
  u16* wob  = wqb + NWQ;
  u16* qkvb = wob + NWO;
  u16* aob  = qkvb + NQ;

  dim3 blk(256);

  cast_bf16<<<dim3(512), blk, 0, stream>>>(x,     xb,  (int)(NX / 8));
  cast_bf16<<<dim3(256), blk, 0, stream>>>(w_qkv, wqb, (int)(NWQ / 8));
  cast_bf16<<<dim3(128), blk, 0, stream>>>(w_out, wob, (int)(NWO / 8));

  // qkv = x @ w_qkv^T (bf16 out, Q pre-scaled 0.125)
  gemm_bf16_nt<0><<<dim3(S_LEN / 128, QKV_DIM / 128), blk, 0, stream>>>(
      xb, wqb, nullptr, qkvb, nullptr, S_LEN, QKV_DIM, EMB);

  // attention -> bf16
  flash_attn_bf16<<<dim3(768), dim3(128), 0, stream>>>(qkvb, aob);

  // out = attn @ w_out^T + b_out (fp32)
  gemm_bf16_nt<1><<<dim3(S_LEN / 128, EMB / 128), blk, 0, stream>>>(
      aob, wob, b_out, nullptr, out, S_LEN, EMB, EMB);
}

// Round 6
// 164.964 us; speedup vs baseline: 7.4253x; 1.3338x over previous
//
#include <hip/hip_runtime.h>
#include <hip/hip_bf16.h>

constexpr int S_LEN   = 4096;
constexpr int EMB     = 768;
constexpr int NH      = 12;
constexpr int DK      = 64;
constexpr int QKV_DIM = 3 * EMB;   // 2304
constexpr int NSPLIT  = 2;
constexpr int TSPLIT  = S_LEN / NSPLIT;  // 2048

typedef short bf16x8 __attribute__((ext_vector_type(8)));
typedef float f32x4  __attribute__((ext_vector_type(4)));
typedef unsigned short u16;

// f32 -> bf16 round-to-nearest-even
__device__ inline u16 f2bf(float x) {
  unsigned u = __float_as_uint(x);
  unsigned r = u + 0x7fffu + ((u >> 16) & 1u);
  return (u16)(r >> 16);
}
__device__ inline float bf2f(u16 h) {
  return __uint_as_float(((unsigned)h) << 16);
}

__device__ inline void gld16(unsigned* lds, const unsigned* g) {
  __builtin_amdgcn_global_load_lds(
      (const __attribute__((address_space(1))) unsigned*)g,
      (__attribute__((address_space(3))) unsigned*)lds, 16, 0, 0);
}

// ---------------------------------------------------------------------------
// fp32 -> bf16 cast (8 elems/thread, grid-stride)
// ---------------------------------------------------------------------------
__global__ __launch_bounds__(256) void cast_bf16(
    const float* __restrict__ src, u16* __restrict__ dst, int n8)
{
  for (int i = blockIdx.x * 256 + threadIdx.x; i < n8; i += gridDim.x * 256) {
    float4 a = reinterpret_cast<const float4*>(src)[2 * i + 0];
    float4 b = reinterpret_cast<const float4*>(src)[2 * i + 1];
    ushort4 h0, h1;
    const float* ap = reinterpret_cast<const float*>(&a);
    const float* bp = reinterpret_cast<const float*>(&b);
#pragma unroll
    for (int j = 0; j < 4; ++j) {
      reinterpret_cast<u16*>(&h0)[j] = f2bf(ap[j]);
      reinterpret_cast<u16*>(&h1)[j] = f2bf(bp[j]);
    }
    reinterpret_cast<ushort4*>(dst)[2 * i + 0] = h0;
    reinterpret_cast<ushort4*>(dst)[2 * i + 1] = h1;
  }
}

// ---------------------------------------------------------------------------
// bf16 NT-GEMM (unchanged from R5): C[M,N] = A[M,K] @ B[N,K]^T, fp32 accum.
// ---------------------------------------------------------------------------
template<int MODE>
__global__ __launch_bounds__(256) void gemm_bf16_nt(
    const u16* __restrict__ A, const u16* __restrict__ B,
    const float* __restrict__ bias,
    u16* __restrict__ Cb, float* __restrict__ Cf,
    int M, int N, int K)
{
  __shared__ __align__(16) u16 sA[128 * 64];
  __shared__ __align__(16) u16 sB[128 * 64];

  const int tid  = threadIdx.x;
  const int w    = tid >> 6;
  const int l    = tid & 63;
  const int lg   = l >> 4;
  const int lr   = l & 15;
  const int wr   = w >> 1;
  const int wc   = w & 1;
  const int brow = blockIdx.x * 128;
  const int bcol = blockIdx.y * 128;

  const int srow = l >> 3;
  const int sslot = l & 7;

  f32x4 acc[4][4] = {};

  for (int k0 = 0; k0 < K; k0 += 64) {
#pragma unroll
    for (int cc = 0; cc < 4; ++cc) {
      int c = w * 4 + cc;
      int row = c * 8 + srow;
      int kswz = (sslot ^ (row & 7)) * 8;
      size_t aoff = (size_t)(brow + row) * K + k0 + kswz;
      size_t boff = (size_t)(bcol + row) * K + k0 + kswz;
      gld16((unsigned*)(sA + c * 512), (const unsigned*)(A + aoff));
      gld16((unsigned*)(sB + c * 512), (const unsigned*)(B + boff));
    }
    __syncthreads();

#pragma unroll
    for (int ks = 0; ks < 2; ++ks) {
      bf16x8 fa[4], fb[4];
#pragma unroll
      for (int i = 0; i < 4; ++i) {
        int arow = wr * 64 + i * 16 + lr;
        int brow_ = wc * 64 + i * 16 + lr;
        fa[i] = *reinterpret_cast<const bf16x8*>(
            &sA[arow * 64 + (((lg + 4 * ks) ^ (arow & 7)) << 3)]);
        fb[i] = *reinterpret_cast<const bf16x8*>(
            &sB[brow_ * 64 + (((lg + 4 * ks) ^ (brow_ & 7)) << 3)]);
      }
#pragma unroll
      for (int mi = 0; mi < 4; ++mi)
#pragma unroll
        for (int ni = 0; ni < 4; ++ni)
          acc[mi][ni] = __builtin_amdgcn_mfma_f32_16x16x32_bf16(
              fa[mi], fb[ni], acc[mi][ni], 0, 0, 0);
    }
    __syncthreads();
  }

  if (MODE == 0) {
    const float qscale = (bcol < EMB) ? 0.125f : 1.0f;
#pragma unroll
    for (int mi = 0; mi < 4; ++mi)
#pragma unroll
      for (int ni = 0; ni < 4; ++ni)
#pragma unroll
        for (int r = 0; r < 4; ++r) {
          size_t m = brow + wr * 64 + mi * 16 + 4 * lg + r;
          size_t n = bcol + wc * 64 + ni * 16 + lr;
          Cb[m * N + n] = f2bf(acc[mi][ni][r] * qscale);
        }
  } else {
#pragma unroll
    for (int mi = 0; mi < 4; ++mi)
#pragma unroll
      for (int ni = 0; ni < 4; ++ni)
#pragma unroll
        for (int r = 0; r < 4; ++r) {
          size_t m = brow + wr * 64 + mi * 16 + 4 * lg + r;
          size_t n = bcol + wc * 64 + ni * 16 + lr;
          Cf[m * N + n] = acc[mi][ni][r] + bias[n];
        }
  }
}

// ---------------------------------------------------------------------------
// Flash attention split-t (2 splits), all-bf16 MFMA, O^T accumulation.
// Block = 128 thr = 2 waves; q-tile 64; grid 1536 = 12 h x 64 qt x 2 split
// = exactly 6 blocks/CU (12 waves/CU).
// Swizzle key (row^(row>>3))&7: varies with BOTH row&7 and row>>3 -> V
// transpose writes (d&7 const per step) now conflict-free; all reads 2-way max.
// K staged via global_load_lds (linear dest, pre-swizzled source).
// PV computed as mfma(A=V^T, B=P) -> acc holds O^T (row=d, col=q=lr), so
// softmax state (per-lane q=lr) rescales acc with ZERO cross-lane shuffles.
// Output: unnormalized partial sums (f32) + per-row (m, l) for combine.
// ---------------------------------------------------------------------------
__device__ inline int key7(int row) { return (row ^ (row >> 3)) & 7; }
__device__ inline int swz16(int row, int s) {          // u16 idx; 16B slot s
  return row * 64 + ((s ^ key7(row)) << 3);
}
__device__ inline int swz32(int row, int p) {          // u32 idx; p=0..31
  return row * 32 + ((((p >> 2) ^ key7(row)) << 2) | (p & 3));
}

__global__ __launch_bounds__(128, 3) void flash_split(
    const u16* __restrict__ qkv, float* __restrict__ Sp,
    float2* __restrict__ mlp)
{
  __shared__ __align__(16) u16 Ks[64 * 64];
  __shared__ __align__(16) u16 Vt[64 * 64];
  __shared__ __align__(16) u16 Ps[2][32 * 64];

  const int tid = threadIdx.x;
  const int w   = tid >> 6;
  const int l   = tid & 63;
  const int lg  = l >> 4;
  const int lr  = l & 15;

  // XCD swizzle: 1536 = 8 x 192
  const int bid   = blockIdx.x;
  const int sbid  = (bid & 7) * 192 + (bid >> 3);
  const int split = sbid & 1;
  const int qb    = ((sbid >> 1) & 63) * 64;
  const int h     = sbid >> 7;            // 0..11
  const int tbeg  = split * TSPLIT;

  unsigned* Pw   = (unsigned*)Ps[w];
  unsigned* Vt32 = (unsigned*)Vt;

  // Q fragments (MFMA B-operand: col=lr -> q, k = d = ks*32 + lg*8 + j)
  bf16x8 qf_[2][2];
#pragma unroll
  for (int qf = 0; qf < 2; ++qf)
#pragma unroll
    for (int ks = 0; ks < 2; ++ks)
      qf_[qf][ks] = *reinterpret_cast<const bf16x8*>(
          qkv + (size_t)(qb + w * 32 + qf * 16 + lr) * QKV_DIM + h * DK + ks * 32 + lg * 8);

  float m_[2] = {-1e30f, -1e30f};
  float ls[2] = {0.0f, 0.0f};
  f32x4 acc[2][4] = {};

  const int tq  = tid >> 3;   // 0..15 (V staging: t-quad)
  const int vgs = tid & 7;    // d-slot

  for (int t0 = tbeg; t0 < tbeg + TSPLIT; t0 += 64) {
    // ---- stage K via global_load_lds: linear dest, pre-swizzled source ----
#pragma unroll
    for (int c = 0; c < 4; ++c) {
      int idx = (c * 2 + w) * 64 + l;     // contiguous per (c,w): dest = idx*16B
      int t = idx >> 3, g = idx & 7;
      int gs = g ^ key7(t);
      gld16((unsigned*)(Ks + idx * 8),
            (const unsigned*)(qkv + (size_t)(t0 + t) * QKV_DIM + EMB + h * DK + gs * 8));
    }
    // ---- stage V transposed Vt[d][t] (reg-staged, swizzled b64 writes) ----
    {
      size_t src = (size_t)(t0 + 4 * tq) * QKV_DIM + 2 * EMB + h * DK + vgs * 8;
      uint4 r0 = *reinterpret_cast<const uint4*>(qkv + src);
      uint4 r1 = *reinterpret_cast<const uint4*>(qkv + src + QKV_DIM);
      uint4 r2 = *reinterpret_cast<const uint4*>(qkv + src + 2 * QKV_DIM);
      uint4 r3 = *reinterpret_cast<const uint4*>(qkv + src + 3 * QKV_DIM);
      const u16* e0 = reinterpret_cast<const u16*>(&r0);
      const u16* e1 = reinterpret_cast<const u16*>(&r1);
      const u16* e2 = reinterpret_cast<const u16*>(&r2);
      const u16* e3 = reinterpret_cast<const u16*>(&r3);
#pragma unroll
      for (int j = 0; j < 8; ++j) {
        int d = vgs * 8 + j;
        uint2 pv;
        pv.x = (unsigned)e0[j] | ((unsigned)e1[j] << 16);
        pv.y = (unsigned)e2[j] | ((unsigned)e3[j] << 16);
        *reinterpret_cast<uint2*>(&Vt32[swz32(d, 2 * tq)]) = pv;
      }
    }
    __syncthreads();

    // ---- QK^T (A=K rows=t, B=Q cols=q): per-lane q = lr ----
    f32x4 sc[2][4] = {};
#pragma unroll
    for (int tt = 0; tt < 4; ++tt)
#pragma unroll
      for (int ks = 0; ks < 2; ++ks) {
        bf16x8 kf = *reinterpret_cast<const bf16x8*>(&Ks[swz16(tt * 16 + lr, 4 * ks + lg)]);
#pragma unroll
        for (int qf = 0; qf < 2; ++qf)
          sc[qf][tt] = __builtin_amdgcn_mfma_f32_16x16x32_bf16(
              kf, qf_[qf][ks], sc[qf][tt], 0, 0, 0);
      }

    // ---- per-lane online softmax (own q = lr; reduce over lg) ----
    float scl[2];
#pragma unroll
    for (int qf = 0; qf < 2; ++qf) {
      float mx = sc[qf][0][0];
#pragma unroll
      for (int tt = 0; tt < 4; ++tt)
#pragma unroll
        for (int r = 0; r < 4; ++r) mx = fmaxf(mx, sc[qf][tt][r]);
      mx = fmaxf(mx, __shfl_xor(mx, 16));
      mx = fmaxf(mx, __shfl_xor(mx, 32));
      float mn = fmaxf(m_[qf], mx);
      scl[qf] = __expf(m_[qf] - mn);
      float sum = 0.0f;
#pragma unroll
      for (int tt = 0; tt < 4; ++tt)
#pragma unroll
        for (int r = 0; r < 4; ++r) {
          float p = __expf(sc[qf][tt][r] - mn);
          sc[qf][tt][r] = p;
          sum += p;
        }
      sum += __shfl_xor(sum, 16);
      sum += __shfl_xor(sum, 32);
      ls[qf] = ls[qf] * scl[qf] + sum;
      m_[qf] = mn;
    }

    // ---- rescale acc: q = col = lr -> scl is already in-lane, no shuffles --
#pragma unroll
    for (int qf = 0; qf < 2; ++qf)
#pragma unroll
      for (int dt = 0; dt < 4; ++dt)
#pragma unroll
        for (int r = 0; r < 4; ++r) acc[qf][dt][r] *= scl[qf];

    // ---- P -> bf16 pairs into per-wave LDS ----
#pragma unroll
    for (int qf = 0; qf < 2; ++qf) {
      int qrow = qf * 16 + lr;
#pragma unroll
      for (int tt = 0; tt < 4; ++tt)
#pragma unroll
        for (int pr = 0; pr < 2; ++pr) {
          u16 b0 = f2bf(sc[qf][tt][2 * pr + 0]);
          u16 b1 = f2bf(sc[qf][tt][2 * pr + 1]);
          Pw[swz32(qrow, 8 * tt + 2 * lg + pr)] = (unsigned)b0 | ((unsigned)b1 << 16);
        }
    }

    // ---- PV flipped: acc[qf][dt] = V^T @ P -> O^T (row=d, col=q=lr) ----
#pragma unroll
    for (int ks = 0; ks < 2; ++ks) {
      bf16x8 pa[2];
#pragma unroll
      for (int qf = 0; qf < 2; ++qf)
        pa[qf] = *reinterpret_cast<const bf16x8*>(&Ps[w][swz16(qf * 16 + lr, 4 * ks + lg)]);
#pragma unroll
      for (int dt = 0; dt < 4; ++dt) {
        bf16x8 vf = *reinterpret_cast<const bf16x8*>(&Vt[swz16(dt * 16 + lr, 4 * ks + lg)]);
#pragma unroll
        for (int qf = 0; qf < 2; ++qf)
          acc[qf][dt] = __builtin_amdgcn_mfma_f32_16x16x32_bf16(
              vf, pa[qf], acc[qf][dt], 0, 0, 0);
      }
    }
    __syncthreads();
  }

  // ---- store unnormalized partial O (f32) + (m, l) per q-row ----
#pragma unroll
  for (int qf = 0; qf < 2; ++qf) {
    int q = qb + w * 32 + qf * 16 + lr;
    size_t base = ((size_t)split * S_LEN + q) * EMB + h * DK;
#pragma unroll
    for (int dt = 0; dt < 4; ++dt)
      *reinterpret_cast<float4*>(&Sp[base + dt * 16 + 4 * lg]) =
          *reinterpret_cast<float4*>(&acc[qf][dt]);
    if (lg == 0)
      mlp[((size_t)split * NH + h) * S_LEN + q] = make_float2(m_[qf], ls[qf]);
  }
}

// ---------------------------------------------------------------------------
// Combine the 2 split partials: O = (w0*S0 + w1*S1) / (w0*l0 + w1*l1), bf16.
// ---------------------------------------------------------------------------
__global__ __launch_bounds__(256) void combine_splits(
    const float* __restrict__ Sp, const float2* __restrict__ mlp,
    u16* __restrict__ ao)
{
  constexpr int N4 = S_LEN * EMB / 4;    // float4 chunks per split
  for (int i = blockIdx.x * 256 + threadIdx.x; i < N4; i += gridDim.x * 256) {
    int q = i / 192;                     // 192 float4 per q-row
    int t = i - q * 192;
    int h = t >> 4;                      // 16 float4 per head
    float2 a = mlp[(size_t)h * S_LEN + q];
    float2 b = mlp[(size_t)(NH + h) * S_LEN + q];
    float mm = fmaxf(a.x, b.x);
    float w0 = __expf(a.x - mm), w1 = __expf(b.x - mm);
    float inv = 1.0f / (w0 * a.y + w1 * b.y);
    float4 s0 = reinterpret_cast<const float4*>(Sp)[i];
    float4 s1 = reinterpret_cast<const float4*>(Sp)[N4 + i];
    ushort4 o;
    o.x = f2bf((w0 * s0.x + w1 * s1.x) * inv);
    o.y = f2bf((w0 * s0.y + w1 * s1.y) * inv);
    o.z = f2bf((w0 * s0.z + w1 * s1.z) * inv);
    o.w = f2bf((w0 * s0.w + w1 * s1.w) * inv);
    reinterpret_cast<ushort4*>(ao)[i] = o;
  }
}

// ---------------------------------------------------------------------------
extern "C" void kernel_launch(void* const* d_in, const int* in_sizes, int n_in,
                              void* d_out, int out_size, void* d_ws, size_t ws_size,
                              hipStream_t stream) {
  const float* x     = (const float*)d_in[0];
  const float* w_qkv = (const float*)d_in[1];
  const float* w_out = (const float*)d_in[2];
  const float* b_out = (const float*)d_in[3];
  float* out = (float*)d_out;

  constexpr size_t NX  = (size_t)S_LEN * EMB;
  constexpr size_t NWQ = (size_t)QKV_DIM * EMB;
  constexpr size_t NWO = (size_t)EMB * EMB;
  constexpr size_t NQ  = (size_t)S_LEN * QKV_DIM;

  u16* xb    = (u16*)d_ws;
  u16* wqb   = xb + NX;
  u16* wob   = wqb + NWQ;
  u16* qkvb  = wob + NWO;
  float* Sp  = (float*)(qkvb + NQ);                 // 2 x [4096][768] f32
  float2* mlp = (float2*)(Sp + (size_t)NSPLIT * S_LEN * EMB);
  u16* aob   = xb;   // alias: x planes dead after QKV GEMM

  dim3 blk(256);

  cast_bf16<<<dim3(512), blk, 0, stream>>>(x,     xb,  (int)(NX / 8));
  cast_bf16<<<dim3(256), blk, 0, stream>>>(w_qkv, wqb, (int)(NWQ / 8));
  cast_bf16<<<dim3(128), blk, 0, stream>>>(w_out, wob, (int)(NWO / 8));

  // qkv = x @ w_qkv^T (bf16 out, Q pre-scaled 0.125)
  gemm_bf16_nt<0><<<dim3(S_LEN / 128, QKV_DIM / 128), blk, 0, stream>>>(
      xb, wqb, nullptr, qkvb, nullptr, S_LEN, QKV_DIM, EMB);

  // attention split partials -> combine to bf16
  flash_split<<<dim3(1536), dim3(128), 0, stream>>>(qkvb, Sp, mlp);
  combine_splits<<<dim3(1024), blk, 0, stream>>>(Sp, mlp, aob);

  // out = attn @ w_out^T + b_out (fp32)
  gemm_bf16_nt<1><<<dim3(S_LEN / 128, EMB / 128), blk, 0, stream>>>(
      aob, wob, b_out, nullptr, out, S_LEN, EMB, EMB);
}